// Round 14
// baseline (351.785 us; speedup 1.0000x reference)
//
#include <hip/hip_runtime.h>
#include <math.h>

#define NN 20000
#define NE 160000
#define DH 128

typedef _Float16 f16;
typedef f16 f16x2 __attribute__((ext_vector_type(2)));
typedef f16 f16x4 __attribute__((ext_vector_type(4)));
typedef f16 f16x8 __attribute__((ext_vector_type(8)));
typedef float f32x4 __attribute__((ext_vector_type(4)));
typedef unsigned int uint32;

// ---------------- prep: fused x->f16 convert + degree count ----------------
__global__ void conv_count_kernel(const float* __restrict__ X, f16* __restrict__ XH,
                                  int n4, const int* __restrict__ edst,
                                  int* __restrict__ deg, int ne) {
  int i = blockIdx.x * blockDim.x + threadIdx.x;
  if (i < n4) {
    float4 v = *(const float4*)(X + (size_t)i * 4);
    f16x4 o = {(f16)v.x, (f16)v.y, (f16)v.z, (f16)v.w};
    *(f16x4*)(XH + (size_t)i * 4) = o;
  }
  if (i < ne) atomicAdd(&deg[edst[i]], 1);
}

// ---------------- CSR build (parallel 3-phase, R13) ----------------
__global__ __launch_bounds__(1024) void csr_p1(const int* __restrict__ deg,
                                               int* __restrict__ rowstart,
                                               int* __restrict__ bsum,
                                               int* __restrict__ ghist, int n) {
  __shared__ int wsum[16];
  __shared__ int lhist[64];
  const int tid = threadIdx.x;
  const int lane = tid & 63, w = tid >> 6;
  if (tid < 64) lhist[tid] = 0;
  __syncthreads();
  int i = blockIdx.x * 1024 + tid;
  int d = (i < n) ? deg[i] : 0;
  if (i < n) atomicAdd(&lhist[d < 63 ? d : 63], 1);
  int v = d;
#pragma unroll
  for (int off = 1; off < 64; off <<= 1) {
    int u = __shfl_up(v, off, 64);
    if (lane >= off) v += u;
  }
  if (lane == 63) wsum[w] = v;
  __syncthreads();
  if (w == 0) {
    int t = (lane < 16) ? wsum[lane] : 0;
#pragma unroll
    for (int off = 1; off < 16; off <<= 1) {
      int u = __shfl_up(t, off, 64);
      if (lane >= off) t += u;
    }
    if (lane < 16) wsum[lane] = t;
  }
  __syncthreads();
  int add = (w > 0 ? wsum[w - 1] : 0);
  if (i < n) rowstart[i + 1] = v + add;
  if (tid == 0) bsum[blockIdx.x] = wsum[15];
  if (tid < 64) ghist[blockIdx.x * 64 + tid] = lhist[tid];
}

__global__ void csr_p2(int* __restrict__ bsum, int nb, int* __restrict__ ghist,
                       int* __restrict__ rowstart, int n) {
  const int lane = threadIdx.x;  // 64 threads
  int v = (lane < nb) ? bsum[lane] : 0;
  int orig = v;
#pragma unroll
  for (int off = 1; off < 64; off <<= 1) {
    int u = __shfl_up(v, off, 64);
    if (lane >= off) v += u;
  }
  if (lane < nb) bsum[lane] = v - orig;
  int t = 0;
  for (int b = 0; b < nb; b++) {
    int tmp = ghist[b * 64 + lane];
    ghist[b * 64 + lane] = t;
    t += tmp;
  }
  int incl = t;
#pragma unroll
  for (int off = 1; off < 64; off <<= 1) {
    int u = __shfl_up(incl, off, 64);
    if (lane >= off) incl += u;
  }
  int binstart = n - incl;  // descending buckets (LPT)
  for (int b = 0; b < nb; b++) ghist[b * 64 + lane] += binstart;
  if (lane == 0) rowstart[0] = 0;
}

__global__ __launch_bounds__(1024) void csr_p3(const int* __restrict__ deg,
                                               int* __restrict__ rowstart,
                                               const int* __restrict__ bsum,
                                               const int* __restrict__ ghist,
                                               int* __restrict__ perm, int n) {
  __shared__ int lcur[64];
  const int tid = threadIdx.x;
  if (tid < 64) lcur[tid] = 0;
  __syncthreads();
  int i = blockIdx.x * 1024 + tid;
  if (i < n) {
    rowstart[i + 1] += bsum[blockIdx.x];
    int d = deg[i];
    int b = d < 63 ? d : 63;
    int pos = atomicAdd(&lcur[b], 1);
    perm[ghist[blockIdx.x * 64 + b] + pos] = i;
  }
}

__global__ void scatter_kernel(const int* __restrict__ src, const int* __restrict__ dstp,
                               const int* __restrict__ rowstart, int* __restrict__ cursor,
                               int* __restrict__ csr, int n) {
  int i = blockIdx.x * blockDim.x + threadIdx.x;
  if (i < n) {
    int d = dstp[i];
    int pos = atomicAdd(&cursor[d], 1);
    csr[rowstart[d] + pos] = src[i];
  }
}

// one 16-lane subgroup per row; 16-element bitonic network (deg<=16 covers
// ~99.6% of Poisson(8) rows). Result: ascending src order == insertion sort
// == bitwise-identical csr. perm order -> same-degree rows per wave.
__global__ void sort_kernel(const int* __restrict__ rowstart, int* __restrict__ csr,
                            const int* __restrict__ perm, int n) {
  int idx = blockIdx.x * blockDim.x + threadIdx.x;
  int sub = idx >> 4;
  int u = idx & 15;
  if (sub >= n) return;
  int i = perm[sub];
  int a = rowstart[i], b = rowstart[i + 1];
  int d = b - a;
  if (d <= 1) return;
  if (d <= 16) {
    int v = (u < d) ? csr[a + u] : 0x7FFFFFFF;
#pragma unroll
    for (int k = 2; k <= 16; k <<= 1) {
#pragma unroll
      for (int j = 16; j > 0; j >>= 1) {
        if (j > (k >> 1)) continue;
        int o = __shfl_xor(v, j, 64);
        bool takeMin = (((u & k) == 0) == ((u & j) == 0));
        v = takeMin ? (v < o ? v : o) : (v > o ? v : o);
      }
    }
    if (u < d) csr[a + u] = v;
  } else if (u == 0) {
    for (int j = a + 1; j < b; j++) {
      int v = csr[j];
      int k = j - 1;
      while (k >= a && csr[k] > v) { csr[k + 1] = csr[k]; k--; }
      csr[k + 1] = v;
    }
  }
}

// ---------------- weights: W [128][HC] f32 -> WT [HC][128] f16 ----------------
__global__ __launch_bounds__(256) void transconv_all(
    const float* __restrict__ W0, const float* __restrict__ W1,
    const float* __restrict__ W2, const float* __restrict__ W3,
    const float* __restrict__ W4, const float* __restrict__ W5,
    f16* O0, f16* O1, f16* O2, f16* O3, f16* O4, f16* O5) {
  const float* W; f16* O; int HC;
  switch (blockIdx.z) {
    case 0: W = W0; O = O0; HC = 1024; break;
    case 1: W = W1; O = O1; HC = 1024; break;
    case 2: W = W2; O = O2; HC = 1024; break;
    case 3: W = W3; O = O3; HC = 1024; break;
    case 4: W = W4; O = O4; HC = 512; break;
    default: W = W5; O = O5; HC = 512; break;
  }
  int c0 = blockIdx.x * 32;
  if (c0 >= HC) return;
  __shared__ float t[32][33];
  int k0 = blockIdx.y * 32;
  int tx = threadIdx.x & 31, ty = threadIdx.x >> 5;  // 32 x 8
#pragma unroll
  for (int j = 0; j < 4; j++) {
    int k = k0 + ty + j * 8;
    t[ty + j * 8][tx] = W[(size_t)k * HC + c0 + tx];
  }
  __syncthreads();
#pragma unroll
  for (int j = 0; j < 4; j++) {
    int c = c0 + ty + j * 8;
    O[(size_t)c * 128 + k0 + tx] = (f16)t[tx][ty + j * 8];
  }
}

// ---------------- f16 MFMA GEMM (XCD swizzle + LDS-staged C write) ----------
template <int YB>
__global__ __launch_bounds__(256) void gemm_f16(const f16* __restrict__ A,
                                                const f16* __restrict__ BT,
                                                f16* __restrict__ C, int M, int Nout) {
  const int nx = (M + 127) / 128;
  const int chunk = nx * YB / 8;
  const int bid = blockIdx.x;
  const int p = (bid % 8) * chunk + bid / 8;
  const int bx = p / YB, by = p % YB;

  const int w = threadIdx.x >> 6, lane = threadIdx.x & 63;
  const int wm = w >> 1, wn = w & 1;
  const int row0 = bx * 128 + wm * 64;
  const int col0 = by * 128 + wn * 64;
  const int lr = lane & 15, lk = (lane >> 4) * 8;

  __shared__ f16 ct[128][144];

  f32x4 acc[4][4] = {};
  const f16* Arow[4];
  const f16* Brow[4];
#pragma unroll
  for (int m = 0; m < 4; m++) {
    int r = row0 + m * 16 + lr;
    r = r < M ? r : M - 1;
    Arow[m] = A + (size_t)r * 128 + lk;
  }
#pragma unroll
  for (int n = 0; n < 4; n++) {
    int c = col0 + n * 16 + lr;
    Brow[n] = BT + (size_t)c * 128 + lk;
  }
#pragma unroll
  for (int ks = 0; ks < 4; ks++) {
    f16x8 a[4], b[4];
#pragma unroll
    for (int m = 0; m < 4; m++) a[m] = *(const f16x8*)(Arow[m] + ks * 32);
#pragma unroll
    for (int n = 0; n < 4; n++) b[n] = *(const f16x8*)(Brow[n] + ks * 32);
#pragma unroll
    for (int m = 0; m < 4; m++)
#pragma unroll
      for (int n = 0; n < 4; n++)
        acc[m][n] = __builtin_amdgcn_mfma_f32_16x16x32_f16(a[m], b[n], acc[m][n], 0, 0, 0);
  }
  const int lrow = wm * 64, lcol = wn * 64;
#pragma unroll
  for (int m = 0; m < 4; m++) {
    int rbase = lrow + m * 16 + (lane >> 4) * 4;
#pragma unroll
    for (int r = 0; r < 4; r++) {
#pragma unroll
      for (int n = 0; n < 4; n++) {
        ct[rbase + r][lcol + n * 16 + lr] = (f16)acc[m][n][r];
      }
    }
  }
  __syncthreads();
  const int t = threadIdx.x;
  const int cidx = (t & 15) * 8;
  const int rowblk = bx * 128, colblk = by * 128;
#pragma unroll
  for (int rr = (t >> 4); rr < 128; rr += 16) {
    int gr = rowblk + rr;
    if (gr < M) {
      uint4 v = *(const uint4*)(&ct[rr][cidx]);
      *(uint4*)(C + (size_t)gr * Nout + colblk + cidx) = v;
    }
  }
}

// ---------------- fused GATv2 aggregation (persistent grid-stride) ----------------
struct LV { f16x2 v[4]; };

__device__ __forceinline__ f16x2 bc2(uint32 x) { return __builtin_bit_cast(f16x2, x); }

__device__ __forceinline__ LV load8(const char* __restrict__ base, uint32 off) {
  uint4 r = *(const uint4*)(base + off);
  LV o;
  o.v[0] = bc2(r.x); o.v[1] = bc2(r.y); o.v[2] = bc2(r.z); o.v[3] = bc2(r.w);
  return o;
}

__device__ __forceinline__ f16x2 leaky2(f16x2 z) {
  f16x2 zs = z * (f16)0.2f;
  return __builtin_elementwise_max(z, zs);
}

__device__ __forceinline__ float edot(const LV& x, const f16x2* xr2, const f16x2* att2) {
  float ea = 0.f, eb = 0.f;
  ea = __builtin_amdgcn_fdot2(leaky2(x.v[0] + xr2[0]), att2[0], ea, false);
  eb = __builtin_amdgcn_fdot2(leaky2(x.v[1] + xr2[1]), att2[1], eb, false);
  ea = __builtin_amdgcn_fdot2(leaky2(x.v[2] + xr2[2]), att2[2], ea, false);
  eb = __builtin_amdgcn_fdot2(leaky2(x.v[3] + xr2[3]), att2[3], eb, false);
  return ea + eb;
}

template <int PAT>
__device__ __forceinline__ float swz(float x) {
  return __int_as_float(__builtin_amdgcn_ds_swizzle(__float_as_int(x), PAT));
}

__device__ __forceinline__ void red16x4(float& a, float& b, float& c, float& d) {
  a += swz<0x041F>(a); b += swz<0x041F>(b); c += swz<0x041F>(c); d += swz<0x041F>(d);
  a += swz<0x081F>(a); b += swz<0x081F>(b); c += swz<0x081F>(c); d += swz<0x081F>(d);
  a += swz<0x101F>(a); b += swz<0x101F>(b); c += swz<0x101F>(c); d += swz<0x101F>(d);
  a += swz<0x201F>(a); b += swz<0x201F>(b); c += swz<0x201F>(c); d += swz<0x201F>(d);
}
__device__ __forceinline__ float red16(float a) {
  a += swz<0x041F>(a);
  a += swz<0x081F>(a);
  a += swz<0x101F>(a);
  a += swz<0x201F>(a);
  return a;
}

// Persistent: grid = 1024 blocks (4/CU resident), grid-stride over perm groups.
template <int H, int DG, bool RELU, bool WF32, int LGROW, int XROFF_B>
__global__ __launch_bounds__(H * DG * 64) void agg_kernel(
    const f16* __restrict__ h_in, const char* __restrict__ xlr8,
    const float* __restrict__ att, const float* __restrict__ bias,
    const int* __restrict__ csr, const int* __restrict__ rowstart,
    const int* __restrict__ perm, int ngrp,
    float* __restrict__ h_out, f16* __restrict__ hh) {
  __shared__ float headout[H][4 * DG][DH];
  __shared__ int nodes[4 * DG];
  const int wv = threadIdx.x >> 6;
  const int h = wv & (H - 1);
  const int dg = wv / H;
  const int lane = threadIdx.x & 63;
  const int g = lane >> 4, u = lane & 15;
  const int c0 = u * 8;
  const uint32 lane_off = (uint32)(h * DH + c0) * 2;

  // loop-invariant: attention fragments
  f16x2 att2[4];
  {
    const float* ap = att + h * DH + c0;
    float a0[8];
    *(float4*)a0 = *(const float4*)ap;
    *(float4*)(a0 + 4) = *(const float4*)(ap + 4);
#pragma unroll
    for (int q = 0; q < 4; q++) att2[q] = f16x2{(f16)a0[2 * q], (f16)a0[2 * q + 1]};
  }

  for (int grp = blockIdx.x; grp < ngrp; grp += gridDim.x) {
    __syncthreads();  // protect nodes/headout reuse across iterations
    if (threadIdx.x < 4 * DG) nodes[threadIdx.x] = perm[grp * 4 * DG + threadIdx.x];
    const int dst = perm[grp * 4 * DG + dg * 4 + g];

    f16x2 xr2[4];
    {
      LV xrv = load8(xlr8, ((uint32)dst << LGROW) + XROFF_B + lane_off);
#pragma unroll
      for (int q = 0; q < 4; q++) xr2[q] = xrv.v[q];
    }

    const int js = rowstart[dst], je = rowstart[dst + 1];

    // self loop seed
    float m, s;
    f16x2 acc[4];
    {
      LV xv = load8(xlr8, ((uint32)dst << LGROW) + lane_off);
      m = red16(edot(xv, xr2, att2));
      s = 1.f;
#pragma unroll
      for (int q = 0; q < 4; q++) acc[q] = xv.v[q];
    }

    // 4-deep prefetch over CSR row (indices clamped to je-1)
    LV pf0, pf1, pf2, pf3;
    {
      int ja = js < je ? js : je - 1;
      int jb = js + 1 < je ? js + 1 : je - 1;
      int jc = js + 2 < je ? js + 2 : je - 1;
      int jd = js + 3 < je ? js + 3 : je - 1;
      if (js < je) {
        pf0 = load8(xlr8, ((uint32)csr[ja] << LGROW) + lane_off);
        pf1 = load8(xlr8, ((uint32)csr[jb] << LGROW) + lane_off);
        pf2 = load8(xlr8, ((uint32)csr[jc] << LGROW) + lane_off);
        pf3 = load8(xlr8, ((uint32)csr[jd] << LGROW) + lane_off);
      }
    }

    int j = js;
    for (; j + 3 < je; j += 4) {
      LV cv0 = pf0, cv1 = pf1, cv2 = pf2, cv3 = pf3;
      int ja = j + 4 < je ? j + 4 : je - 1;
      int jb = j + 5 < je ? j + 5 : je - 1;
      int jc = j + 6 < je ? j + 6 : je - 1;
      int jd = j + 7 < je ? j + 7 : je - 1;
      pf0 = load8(xlr8, ((uint32)csr[ja] << LGROW) + lane_off);
      pf1 = load8(xlr8, ((uint32)csr[jb] << LGROW) + lane_off);
      pf2 = load8(xlr8, ((uint32)csr[jc] << LGROW) + lane_off);
      pf3 = load8(xlr8, ((uint32)csr[jd] << LGROW) + lane_off);

      float e0 = edot(cv0, xr2, att2);
      float e1 = edot(cv1, xr2, att2);
      float e2 = edot(cv2, xr2, att2);
      float e3 = edot(cv3, xr2, att2);
      red16x4(e0, e1, e2, e3);

      float mn = fmaxf(fmaxf(fmaxf(m, e0), fmaxf(e1, e2)), e3);
      float a = __expf(m - mn);
      float p0 = __expf(e0 - mn);
      float p1 = __expf(e1 - mn);
      float p2 = __expf(e2 - mn);
      float p3 = __expf(e3 - mn);
      s = s * a + ((p0 + p1) + (p2 + p3));
      f16 ah = (f16)a, g0 = (f16)p0, g1 = (f16)p1, g2 = (f16)p2, g3 = (f16)p3;
      f16x2 a2 = {ah, ah}, q0 = {g0, g0}, q1 = {g1, g1}, q2 = {g2, g2}, q3 = {g3, g3};
#pragma unroll
      for (int q = 0; q < 4; q++) {
        f16x2 t = acc[q] * a2;
        t = cv0.v[q] * q0 + t;
        t = cv1.v[q] * q1 + t;
        t = cv2.v[q] * q2 + t;
        t = cv3.v[q] * q3 + t;
        acc[q] = t;
      }
      m = mn;
    }
    // tail: consume remaining prefetched edges one at a time
    for (int t = 0; j < je; j++, t++) {
      LV cv = (t == 0) ? pf0 : (t == 1) ? pf1 : pf2;
      float e = red16(edot(cv, xr2, att2));
      float mn = fmaxf(m, e);
      float a = __expf(m - mn);
      float p = __expf(e - mn);
      s = s * a + p;
      f16 ah = (f16)a, gh = (f16)p;
      f16x2 a2 = {ah, ah}, p2 = {gh, gh};
#pragma unroll
      for (int q = 0; q < 4; q++) acc[q] = acc[q] * a2 + cv.v[q] * p2;
      m = mn;
    }

    float inv = 1.f / s;
#pragma unroll
    for (int q = 0; q < 4; q++) {
      headout[h][dg * 4 + g][c0 + 2 * q] = (float)acc[q][0] * inv;
      headout[h][dg * 4 + g][c0 + 2 * q + 1] = (float)acc[q][1] * inv;
    }
    __syncthreads();
    for (int t = threadIdx.x; t < 4 * DG * DH; t += H * DG * 64) {
      int d = t >> 7, c = t & 127;
      float sum = 0.f;
#pragma unroll
      for (int q = 0; q < H; q++) sum += headout[q][d][c];
      float r = sum * (1.f / H) + bias[c];
      if (RELU) r = fmaxf(r, 0.f);
      int node = nodes[d];
      float o = r + (float)h_in[(size_t)node * DH + c];
      if (WF32) h_out[(size_t)node * DH + c] = o;
      else hh[(size_t)node * DH + c] = (f16)o;
    }
  }
}

extern "C" void kernel_launch(void* const* d_in, const int* in_sizes, int n_in,
                              void* d_out, int out_size, void* d_ws, size_t ws_size,
                              hipStream_t stream) {
  const float* x = (const float*)d_in[0];
  const int* ei = (const int*)d_in[1];
  const float* Wl1 = (const float*)d_in[2];
  const float* Wr1 = (const float*)d_in[3];
  const float* att1 = (const float*)d_in[4];
  const float* b1 = (const float*)d_in[5];
  const float* Wl2 = (const float*)d_in[6];
  const float* Wr2 = (const float*)d_in[7];
  const float* att2 = (const float*)d_in[8];
  const float* b2 = (const float*)d_in[9];
  const float* Wl3 = (const float*)d_in[10];
  const float* Wr3 = (const float*)d_in[11];
  const float* att3 = (const float*)d_in[12];
  const float* b3 = (const float*)d_in[13];
  float* out = (float*)d_out;

  char* p = (char*)d_ws;
  f16* xlr = (f16*)p; p += (size_t)NN * 2048 * 2;
  f16* xh  = (f16*)p; p += (size_t)NN * DH * 2;
  f16* h1h = (f16*)p; p += (size_t)NN * DH * 2;
  f16* h2h = (f16*)p; p += (size_t)NN * DH * 2;
  f16* WT1 = (f16*)p; p += (size_t)2048 * 128 * 2;
  f16* WT2 = (f16*)p; p += (size_t)2048 * 128 * 2;
  f16* WT3 = (f16*)p; p += (size_t)1024 * 128 * 2;
  int* deg      = (int*)p; p += (size_t)NN * 4;
  int* cursor   = (int*)p; p += (size_t)NN * 4;
  int* rowstart = (int*)p; p += (size_t)(NN + 1) * 4;
  int* perm     = (int*)p; p += (size_t)NN * 4;
  int* bsum     = (int*)p; p += (size_t)32 * 4;
  int* ghist    = (int*)p; p += (size_t)20 * 64 * 4;
  int* csr      = (int*)p;

  const int* esrc = ei;
  const int* edst = ei + NE;

  const int nbc = (NN + 1023) / 1024;  // 20 CSR-build blocks

  hipMemsetAsync(deg, 0, sizeof(int) * 2 * NN, stream);  // deg + cursor
  conv_count_kernel<<<(NN * DH / 4 + 255) / 256, 256, 0, stream>>>(
      x, xh, NN * DH / 4, edst, deg, NE);
  csr_p1<<<nbc, 1024, 0, stream>>>(deg, rowstart, bsum, ghist, NN);
  csr_p2<<<1, 64, 0, stream>>>(bsum, nbc, ghist, rowstart, NN);
  csr_p3<<<nbc, 1024, 0, stream>>>(deg, rowstart, bsum, ghist, perm, NN);
  scatter_kernel<<<(NE + 255) / 256, 256, 0, stream>>>(esrc, edst, rowstart, cursor, csr, NE);
  sort_kernel<<<(NN * 16 + 255) / 256, 256, 0, stream>>>(rowstart, csr, perm, NN);
  transconv_all<<<dim3(32, 4, 6), 256, 0, stream>>>(
      Wl1, Wr1, Wl2, Wr2, Wl3, Wr3,
      WT1, WT1 + (size_t)1024 * 128, WT2, WT2 + (size_t)1024 * 128,
      WT3, WT3 + (size_t)512 * 128);

  const int nx = (NN + 127) / 128;  // 157
  const int PG = 1024;              // persistent agg grid: 4 blocks/CU

  // layer 1
  gemm_f16<16><<<nx * 16, 256, 0, stream>>>(xh, WT1, xlr, NN, 2048);
  agg_kernel<8, 1, true, false, 12, 2048><<<PG, 512, 0, stream>>>(
      xh, (const char*)xlr, att1, b1, csr, rowstart, perm, NN / 4, nullptr, h1h);
  // layer 2
  gemm_f16<16><<<nx * 16, 256, 0, stream>>>(h1h, WT2, xlr, NN, 2048);
  agg_kernel<8, 1, true, false, 12, 2048><<<PG, 512, 0, stream>>>(
      h1h, (const char*)xlr, att2, b2, csr, rowstart, perm, NN / 4, nullptr, h2h);
  // layer 3
  gemm_f16<8><<<nx * 8, 256, 0, stream>>>(h2h, WT3, xlr, NN, 1024);
  agg_kernel<4, 2, false, true, 11, 1024><<<PG, 512, 0, stream>>>(
      h2h, (const char*)xlr, att3, b3, csr, rowstart, perm, NN / 8, out, nullptr);
}

// Round 15
// 327.960 us; speedup vs baseline: 1.0726x; 1.0726x over previous
//
#include <hip/hip_runtime.h>
#include <math.h>

#define NN 20000
#define NE 160000
#define DH 128

typedef _Float16 f16;
typedef f16 f16x2 __attribute__((ext_vector_type(2)));
typedef f16 f16x4 __attribute__((ext_vector_type(4)));
typedef f16 f16x8 __attribute__((ext_vector_type(8)));
typedef float f32x4 __attribute__((ext_vector_type(4)));
typedef unsigned int uint32;

// ---------------- prep: fused x->f16 convert + degree count ----------------
__global__ void conv_count_kernel(const float* __restrict__ X, f16* __restrict__ XH,
                                  int n4, const int* __restrict__ edst,
                                  int* __restrict__ deg, int ne) {
  int i = blockIdx.x * blockDim.x + threadIdx.x;
  if (i < n4) {
    float4 v = *(const float4*)(X + (size_t)i * 4);
    f16x4 o = {(f16)v.x, (f16)v.y, (f16)v.z, (f16)v.w};
    *(f16x4*)(XH + (size_t)i * 4) = o;
  }
  if (i < ne) atomicAdd(&deg[edst[i]], 1);
}

// ---------------- CSR build (parallel 3-phase, R13) ----------------
__global__ __launch_bounds__(1024) void csr_p1(const int* __restrict__ deg,
                                               int* __restrict__ rowstart,
                                               int* __restrict__ bsum,
                                               int* __restrict__ ghist, int n) {
  __shared__ int wsum[16];
  __shared__ int lhist[64];
  const int tid = threadIdx.x;
  const int lane = tid & 63, w = tid >> 6;
  if (tid < 64) lhist[tid] = 0;
  __syncthreads();
  int i = blockIdx.x * 1024 + tid;
  int d = (i < n) ? deg[i] : 0;
  if (i < n) atomicAdd(&lhist[d < 63 ? d : 63], 1);
  int v = d;
#pragma unroll
  for (int off = 1; off < 64; off <<= 1) {
    int u = __shfl_up(v, off, 64);
    if (lane >= off) v += u;
  }
  if (lane == 63) wsum[w] = v;
  __syncthreads();
  if (w == 0) {
    int t = (lane < 16) ? wsum[lane] : 0;
#pragma unroll
    for (int off = 1; off < 16; off <<= 1) {
      int u = __shfl_up(t, off, 64);
      if (lane >= off) t += u;
    }
    if (lane < 16) wsum[lane] = t;
  }
  __syncthreads();
  int add = (w > 0 ? wsum[w - 1] : 0);
  if (i < n) rowstart[i + 1] = v + add;
  if (tid == 0) bsum[blockIdx.x] = wsum[15];
  if (tid < 64) ghist[blockIdx.x * 64 + tid] = lhist[tid];
}

__global__ void csr_p2(int* __restrict__ bsum, int nb, int* __restrict__ ghist,
                       int* __restrict__ rowstart, int n) {
  const int lane = threadIdx.x;  // 64 threads
  int v = (lane < nb) ? bsum[lane] : 0;
  int orig = v;
#pragma unroll
  for (int off = 1; off < 64; off <<= 1) {
    int u = __shfl_up(v, off, 64);
    if (lane >= off) v += u;
  }
  if (lane < nb) bsum[lane] = v - orig;
  int t = 0;
  for (int b = 0; b < nb; b++) {
    int tmp = ghist[b * 64 + lane];
    ghist[b * 64 + lane] = t;
    t += tmp;
  }
  int incl = t;
#pragma unroll
  for (int off = 1; off < 64; off <<= 1) {
    int u = __shfl_up(incl, off, 64);
    if (lane >= off) incl += u;
  }
  int binstart = n - incl;  // descending buckets (LPT)
  for (int b = 0; b < nb; b++) ghist[b * 64 + lane] += binstart;
  if (lane == 0) rowstart[0] = 0;
}

__global__ __launch_bounds__(1024) void csr_p3(const int* __restrict__ deg,
                                               int* __restrict__ rowstart,
                                               const int* __restrict__ bsum,
                                               const int* __restrict__ ghist,
                                               int* __restrict__ perm, int n) {
  __shared__ int lcur[64];
  const int tid = threadIdx.x;
  if (tid < 64) lcur[tid] = 0;
  __syncthreads();
  int i = blockIdx.x * 1024 + tid;
  if (i < n) {
    rowstart[i + 1] += bsum[blockIdx.x];
    int d = deg[i];
    int b = d < 63 ? d : 63;
    int pos = atomicAdd(&lcur[b], 1);
    perm[ghist[blockIdx.x * 64 + b] + pos] = i;
  }
}

__global__ void scatter_kernel(const int* __restrict__ src, const int* __restrict__ dstp,
                               const int* __restrict__ rowstart, int* __restrict__ cursor,
                               int* __restrict__ csr, int n) {
  int i = blockIdx.x * blockDim.x + threadIdx.x;
  if (i < n) {
    int d = dstp[i];
    int pos = atomicAdd(&cursor[d], 1);
    csr[rowstart[d] + pos] = src[i];
  }
}

// one 16-lane subgroup per row; 16-element bitonic network (deg<=16 covers
// ~99.6% of Poisson(8) rows). Ascending order == insertion sort result.
__global__ void sort_kernel(const int* __restrict__ rowstart, int* __restrict__ csr,
                            const int* __restrict__ perm, int n) {
  int idx = blockIdx.x * blockDim.x + threadIdx.x;
  int sub = idx >> 4;
  int u = idx & 15;
  if (sub >= n) return;
  int i = perm[sub];
  int a = rowstart[i], b = rowstart[i + 1];
  int d = b - a;
  if (d <= 1) return;
  if (d <= 16) {
    int v = (u < d) ? csr[a + u] : 0x7FFFFFFF;
#pragma unroll
    for (int k = 2; k <= 16; k <<= 1) {
#pragma unroll
      for (int j = 16; j > 0; j >>= 1) {
        if (j > (k >> 1)) continue;
        int o = __shfl_xor(v, j, 64);
        bool takeMin = (((u & k) == 0) == ((u & j) == 0));
        v = takeMin ? (v < o ? v : o) : (v > o ? v : o);
      }
    }
    if (u < d) csr[a + u] = v;
  } else if (u == 0) {
    for (int j = a + 1; j < b; j++) {
      int v = csr[j];
      int k = j - 1;
      while (k >= a && csr[k] > v) { csr[k + 1] = csr[k]; k--; }
      csr[k + 1] = v;
    }
  }
}

// ---------------- weights: W [128][HC] f32 -> WT [HC][128] f16 ----------------
__global__ __launch_bounds__(256) void transconv_all(
    const float* __restrict__ W0, const float* __restrict__ W1,
    const float* __restrict__ W2, const float* __restrict__ W3,
    const float* __restrict__ W4, const float* __restrict__ W5,
    f16* O0, f16* O1, f16* O2, f16* O3, f16* O4, f16* O5) {
  const float* W; f16* O; int HC;
  switch (blockIdx.z) {
    case 0: W = W0; O = O0; HC = 1024; break;
    case 1: W = W1; O = O1; HC = 1024; break;
    case 2: W = W2; O = O2; HC = 1024; break;
    case 3: W = W3; O = O3; HC = 1024; break;
    case 4: W = W4; O = O4; HC = 512; break;
    default: W = W5; O = O5; HC = 512; break;
  }
  int c0 = blockIdx.x * 32;
  if (c0 >= HC) return;
  __shared__ float t[32][33];
  int k0 = blockIdx.y * 32;
  int tx = threadIdx.x & 31, ty = threadIdx.x >> 5;  // 32 x 8
#pragma unroll
  for (int j = 0; j < 4; j++) {
    int k = k0 + ty + j * 8;
    t[ty + j * 8][tx] = W[(size_t)k * HC + c0 + tx];
  }
  __syncthreads();
#pragma unroll
  for (int j = 0; j < 4; j++) {
    int c = c0 + ty + j * 8;
    O[(size_t)c * 128 + k0 + tx] = (f16)t[tx][ty + j * 8];
  }
}

// ---------------- f16 MFMA GEMM (XCD swizzle + LDS-staged C write) ----------
template <int YB>
__global__ __launch_bounds__(256) void gemm_f16(const f16* __restrict__ A,
                                                const f16* __restrict__ BT,
                                                f16* __restrict__ C, int M, int Nout) {
  const int nx = (M + 127) / 128;
  const int chunk = nx * YB / 8;
  const int bid = blockIdx.x;
  const int p = (bid % 8) * chunk + bid / 8;
  const int bx = p / YB, by = p % YB;

  const int w = threadIdx.x >> 6, lane = threadIdx.x & 63;
  const int wm = w >> 1, wn = w & 1;
  const int row0 = bx * 128 + wm * 64;
  const int col0 = by * 128 + wn * 64;
  const int lr = lane & 15, lk = (lane >> 4) * 8;

  __shared__ f16 ct[128][144];

  f32x4 acc[4][4] = {};
  const f16* Arow[4];
  const f16* Brow[4];
#pragma unroll
  for (int m = 0; m < 4; m++) {
    int r = row0 + m * 16 + lr;
    r = r < M ? r : M - 1;
    Arow[m] = A + (size_t)r * 128 + lk;
  }
#pragma unroll
  for (int n = 0; n < 4; n++) {
    int c = col0 + n * 16 + lr;
    Brow[n] = BT + (size_t)c * 128 + lk;
  }
#pragma unroll
  for (int ks = 0; ks < 4; ks++) {
    f16x8 a[4], b[4];
#pragma unroll
    for (int m = 0; m < 4; m++) a[m] = *(const f16x8*)(Arow[m] + ks * 32);
#pragma unroll
    for (int n = 0; n < 4; n++) b[n] = *(const f16x8*)(Brow[n] + ks * 32);
#pragma unroll
    for (int m = 0; m < 4; m++)
#pragma unroll
      for (int n = 0; n < 4; n++)
        acc[m][n] = __builtin_amdgcn_mfma_f32_16x16x32_f16(a[m], b[n], acc[m][n], 0, 0, 0);
  }
  const int lrow = wm * 64, lcol = wn * 64;
#pragma unroll
  for (int m = 0; m < 4; m++) {
    int rbase = lrow + m * 16 + (lane >> 4) * 4;
#pragma unroll
    for (int r = 0; r < 4; r++) {
#pragma unroll
      for (int n = 0; n < 4; n++) {
        ct[rbase + r][lcol + n * 16 + lr] = (f16)acc[m][n][r];
      }
    }
  }
  __syncthreads();
  const int t = threadIdx.x;
  const int cidx = (t & 15) * 8;
  const int rowblk = bx * 128, colblk = by * 128;
#pragma unroll
  for (int rr = (t >> 4); rr < 128; rr += 16) {
    int gr = rowblk + rr;
    if (gr < M) {
      uint4 v = *(const uint4*)(&ct[rr][cidx]);
      *(uint4*)(C + (size_t)gr * Nout + colblk + cidx) = v;
    }
  }
}

// ---------------- fused GATv2 aggregation (R13 one-group-per-block) ----------------
// NOTE (R14 lesson): persistent grid-stride agg REGRESSED (56.7->67us, occ 56->45%):
// the loop-top __syncthreads serializes dst-groups within a block; independent
// 1-shot blocks overlap better via the HW scheduler. Do not reintroduce.
struct LV { f16x2 v[4]; };

__device__ __forceinline__ f16x2 bc2(uint32 x) { return __builtin_bit_cast(f16x2, x); }

__device__ __forceinline__ LV load8(const char* __restrict__ base, uint32 off) {
  uint4 r = *(const uint4*)(base + off);
  LV o;
  o.v[0] = bc2(r.x); o.v[1] = bc2(r.y); o.v[2] = bc2(r.z); o.v[3] = bc2(r.w);
  return o;
}

__device__ __forceinline__ f16x2 leaky2(f16x2 z) {
  f16x2 zs = z * (f16)0.2f;
  return __builtin_elementwise_max(z, zs);
}

__device__ __forceinline__ float edot(const LV& x, const f16x2* xr2, const f16x2* att2) {
  float ea = 0.f, eb = 0.f;
  ea = __builtin_amdgcn_fdot2(leaky2(x.v[0] + xr2[0]), att2[0], ea, false);
  eb = __builtin_amdgcn_fdot2(leaky2(x.v[1] + xr2[1]), att2[1], eb, false);
  ea = __builtin_amdgcn_fdot2(leaky2(x.v[2] + xr2[2]), att2[2], ea, false);
  eb = __builtin_amdgcn_fdot2(leaky2(x.v[3] + xr2[3]), att2[3], eb, false);
  return ea + eb;
}

template <int PAT>
__device__ __forceinline__ float swz(float x) {
  return __int_as_float(__builtin_amdgcn_ds_swizzle(__float_as_int(x), PAT));
}

__device__ __forceinline__ void red16x4(float& a, float& b, float& c, float& d) {
  a += swz<0x041F>(a); b += swz<0x041F>(b); c += swz<0x041F>(c); d += swz<0x041F>(d);
  a += swz<0x081F>(a); b += swz<0x081F>(b); c += swz<0x081F>(c); d += swz<0x081F>(d);
  a += swz<0x101F>(a); b += swz<0x101F>(b); c += swz<0x101F>(c); d += swz<0x101F>(d);
  a += swz<0x201F>(a); b += swz<0x201F>(b); c += swz<0x201F>(c); d += swz<0x201F>(d);
}
__device__ __forceinline__ float red16(float a) {
  a += swz<0x041F>(a);
  a += swz<0x081F>(a);
  a += swz<0x101F>(a);
  a += swz<0x201F>(a);
  return a;
}

// H heads; DG dst-groups per block (block = H*DG waves, 4*DG dsts);
// LGROW: log2 row stride bytes; XROFF_B: byte offset of xr half.
template <int H, int DG, bool RELU, bool WF32, int LGROW, int XROFF_B>
__global__ __launch_bounds__(H * DG * 64) void agg_kernel(
    const f16* __restrict__ h_in, const char* __restrict__ xlr8,
    const float* __restrict__ att, const float* __restrict__ bias,
    const int* __restrict__ csr, const int* __restrict__ rowstart,
    const int* __restrict__ perm,
    float* __restrict__ h_out, f16* __restrict__ hh) {
  __shared__ float headout[H][4 * DG][DH];
  __shared__ int nodes[4 * DG];
  const int wv = threadIdx.x >> 6;
  const int h = wv & (H - 1);
  const int dg = wv / H;
  const int lane = threadIdx.x & 63;
  const int g = lane >> 4, u = lane & 15;
  const int c0 = u * 8;
  if (threadIdx.x < 4 * DG) nodes[threadIdx.x] = perm[blockIdx.x * 4 * DG + threadIdx.x];
  const int dst = perm[blockIdx.x * 4 * DG + dg * 4 + g];
  const uint32 lane_off = (uint32)(h * DH + c0) * 2;

  f16x2 att2[4], xr2[4];
  {
    const float* ap = att + h * DH + c0;
    float a0[8];
    *(float4*)a0 = *(const float4*)ap;
    *(float4*)(a0 + 4) = *(const float4*)(ap + 4);
#pragma unroll
    for (int q = 0; q < 4; q++) att2[q] = f16x2{(f16)a0[2 * q], (f16)a0[2 * q + 1]};
    LV xrv = load8(xlr8, ((uint32)dst << LGROW) + XROFF_B + lane_off);
#pragma unroll
    for (int q = 0; q < 4; q++) xr2[q] = xrv.v[q];
  }

  const int js = rowstart[dst], je = rowstart[dst + 1];

  // self loop seed
  float m, s;
  f16x2 acc[4];
  {
    LV xv = load8(xlr8, ((uint32)dst << LGROW) + lane_off);
    m = red16(edot(xv, xr2, att2));
    s = 1.f;
#pragma unroll
    for (int q = 0; q < 4; q++) acc[q] = xv.v[q];
  }

  // 4-deep prefetch over CSR row (indices clamped to je-1)
  LV pf0, pf1, pf2, pf3;
  {
    int ja = js < je ? js : je - 1;
    int jb = js + 1 < je ? js + 1 : je - 1;
    int jc = js + 2 < je ? js + 2 : je - 1;
    int jd = js + 3 < je ? js + 3 : je - 1;
    if (js < je) {
      pf0 = load8(xlr8, ((uint32)csr[ja] << LGROW) + lane_off);
      pf1 = load8(xlr8, ((uint32)csr[jb] << LGROW) + lane_off);
      pf2 = load8(xlr8, ((uint32)csr[jc] << LGROW) + lane_off);
      pf3 = load8(xlr8, ((uint32)csr[jd] << LGROW) + lane_off);
    }
  }

  int j = js;
  for (; j + 3 < je; j += 4) {
    LV cv0 = pf0, cv1 = pf1, cv2 = pf2, cv3 = pf3;
    int ja = j + 4 < je ? j + 4 : je - 1;
    int jb = j + 5 < je ? j + 5 : je - 1;
    int jc = j + 6 < je ? j + 6 : je - 1;
    int jd = j + 7 < je ? j + 7 : je - 1;
    pf0 = load8(xlr8, ((uint32)csr[ja] << LGROW) + lane_off);
    pf1 = load8(xlr8, ((uint32)csr[jb] << LGROW) + lane_off);
    pf2 = load8(xlr8, ((uint32)csr[jc] << LGROW) + lane_off);
    pf3 = load8(xlr8, ((uint32)csr[jd] << LGROW) + lane_off);

    float e0 = edot(cv0, xr2, att2);
    float e1 = edot(cv1, xr2, att2);
    float e2 = edot(cv2, xr2, att2);
    float e3 = edot(cv3, xr2, att2);
    red16x4(e0, e1, e2, e3);

    float mn = fmaxf(fmaxf(fmaxf(m, e0), fmaxf(e1, e2)), e3);
    float a = __expf(m - mn);
    float p0 = __expf(e0 - mn);
    float p1 = __expf(e1 - mn);
    float p2 = __expf(e2 - mn);
    float p3 = __expf(e3 - mn);
    s = s * a + ((p0 + p1) + (p2 + p3));
    f16 ah = (f16)a, g0 = (f16)p0, g1 = (f16)p1, g2 = (f16)p2, g3 = (f16)p3;
    f16x2 a2 = {ah, ah}, q0 = {g0, g0}, q1 = {g1, g1}, q2 = {g2, g2}, q3 = {g3, g3};
#pragma unroll
    for (int q = 0; q < 4; q++) {
      f16x2 t = acc[q] * a2;
      t = cv0.v[q] * q0 + t;
      t = cv1.v[q] * q1 + t;
      t = cv2.v[q] * q2 + t;
      t = cv3.v[q] * q3 + t;
      acc[q] = t;
    }
    m = mn;
  }
  // tail: consume remaining prefetched edges one at a time
  for (int t = 0; j < je; j++, t++) {
    LV cv = (t == 0) ? pf0 : (t == 1) ? pf1 : pf2;
    float e = red16(edot(cv, xr2, att2));
    float mn = fmaxf(m, e);
    float a = __expf(m - mn);
    float p = __expf(e - mn);
    s = s * a + p;
    f16 ah = (f16)a, gh = (f16)p;
    f16x2 a2 = {ah, ah}, p2 = {gh, gh};
#pragma unroll
    for (int q = 0; q < 4; q++) acc[q] = acc[q] * a2 + cv.v[q] * p2;
    m = mn;
  }

  float inv = 1.f / s;
#pragma unroll
  for (int q = 0; q < 4; q++) {
    headout[h][dg * 4 + g][c0 + 2 * q] = (float)acc[q][0] * inv;
    headout[h][dg * 4 + g][c0 + 2 * q + 1] = (float)acc[q][1] * inv;
  }
  __syncthreads();
  for (int t = threadIdx.x; t < 4 * DG * DH; t += H * DG * 64) {
    int d = t >> 7, c = t & 127;
    float sum = 0.f;
#pragma unroll
    for (int q = 0; q < H; q++) sum += headout[q][d][c];
    float r = sum * (1.f / H) + bias[c];
    if (RELU) r = fmaxf(r, 0.f);
    int node = nodes[d];
    float o = r + (float)h_in[(size_t)node * DH + c];
    if (WF32) h_out[(size_t)node * DH + c] = o;
    else hh[(size_t)node * DH + c] = (f16)o;
  }
}

extern "C" void kernel_launch(void* const* d_in, const int* in_sizes, int n_in,
                              void* d_out, int out_size, void* d_ws, size_t ws_size,
                              hipStream_t stream) {
  const float* x = (const float*)d_in[0];
  const int* ei = (const int*)d_in[1];
  const float* Wl1 = (const float*)d_in[2];
  const float* Wr1 = (const float*)d_in[3];
  const float* att1 = (const float*)d_in[4];
  const float* b1 = (const float*)d_in[5];
  const float* Wl2 = (const float*)d_in[6];
  const float* Wr2 = (const float*)d_in[7];
  const float* att2 = (const float*)d_in[8];
  const float* b2 = (const float*)d_in[9];
  const float* Wl3 = (const float*)d_in[10];
  const float* Wr3 = (const float*)d_in[11];
  const float* att3 = (const float*)d_in[12];
  const float* b3 = (const float*)d_in[13];
  float* out = (float*)d_out;

  char* p = (char*)d_ws;
  f16* xlr = (f16*)p; p += (size_t)NN * 2048 * 2;
  f16* xh  = (f16*)p; p += (size_t)NN * DH * 2;
  f16* h1h = (f16*)p; p += (size_t)NN * DH * 2;
  f16* h2h = (f16*)p; p += (size_t)NN * DH * 2;
  f16* WT1 = (f16*)p; p += (size_t)2048 * 128 * 2;
  f16* WT2 = (f16*)p; p += (size_t)2048 * 128 * 2;
  f16* WT3 = (f16*)p; p += (size_t)1024 * 128 * 2;
  int* deg      = (int*)p; p += (size_t)NN * 4;
  int* cursor   = (int*)p; p += (size_t)NN * 4;
  int* rowstart = (int*)p; p += (size_t)(NN + 1) * 4;
  int* perm     = (int*)p; p += (size_t)NN * 4;
  int* bsum     = (int*)p; p += (size_t)32 * 4;
  int* ghist    = (int*)p; p += (size_t)20 * 64 * 4;
  int* csr      = (int*)p;

  const int* esrc = ei;
  const int* edst = ei + NE;

  const int nbc = (NN + 1023) / 1024;  // 20 CSR-build blocks

  hipMemsetAsync(deg, 0, sizeof(int) * 2 * NN, stream);  // deg + cursor
  conv_count_kernel<<<(NN * DH / 4 + 255) / 256, 256, 0, stream>>>(
      x, xh, NN * DH / 4, edst, deg, NE);
  csr_p1<<<nbc, 1024, 0, stream>>>(deg, rowstart, bsum, ghist, NN);
  csr_p2<<<1, 64, 0, stream>>>(bsum, nbc, ghist, rowstart, NN);
  csr_p3<<<nbc, 1024, 0, stream>>>(deg, rowstart, bsum, ghist, perm, NN);
  scatter_kernel<<<(NE + 255) / 256, 256, 0, stream>>>(esrc, edst, rowstart, cursor, csr, NE);
  sort_kernel<<<(NN * 16 + 255) / 256, 256, 0, stream>>>(rowstart, csr, perm, NN);
  transconv_all<<<dim3(32, 4, 6), 256, 0, stream>>>(
      Wl1, Wr1, Wl2, Wr2, Wl3, Wr3,
      WT1, WT1 + (size_t)1024 * 128, WT2, WT2 + (size_t)1024 * 128,
      WT3, WT3 + (size_t)512 * 128);

  const int nx = (NN + 127) / 128;  // 157

  // layer 1
  gemm_f16<16><<<nx * 16, 256, 0, stream>>>(xh, WT1, xlr, NN, 2048);
  agg_kernel<8, 1, true, false, 12, 2048><<<NN / 4, 512, 0, stream>>>(
      xh, (const char*)xlr, att1, b1, csr, rowstart, perm, nullptr, h1h);
  // layer 2
  gemm_f16<16><<<nx * 16, 256, 0, stream>>>(h1h, WT2, xlr, NN, 2048);
  agg_kernel<8, 1, true, false, 12, 2048><<<NN / 4, 512, 0, stream>>>(
      h1h, (const char*)xlr, att2, b2, csr, rowstart, perm, nullptr, h2h);
  // layer 3
  gemm_f16<8><<<nx * 8, 256, 0, stream>>>(h2h, WT3, xlr, NN, 1024);
  agg_kernel<4, 2, false, true, 11, 1024><<<NN / 8, 512, 0, stream>>>(
      h2h, (const char*)xlr, att3, b3, csr, rowstart, perm, out, nullptr);
}

// Round 16
// 312.043 us; speedup vs baseline: 1.1274x; 1.0510x over previous
//
#include <hip/hip_runtime.h>
#include <math.h>

#define NN 20000
#define NE 160000
#define DH 128

typedef _Float16 f16;
typedef f16 f16x2 __attribute__((ext_vector_type(2)));
typedef f16 f16x4 __attribute__((ext_vector_type(4)));
typedef f16 f16x8 __attribute__((ext_vector_type(8)));
typedef float f32x4 __attribute__((ext_vector_type(4)));
typedef unsigned int uint32;
typedef unsigned char u8;

// ---------------- prep: fused x->f16 convert + degree count ----------------
__global__ void conv_count_kernel(const float* __restrict__ X, f16* __restrict__ XH,
                                  int n4, const int* __restrict__ edst,
                                  int* __restrict__ deg, int ne) {
  int i = blockIdx.x * blockDim.x + threadIdx.x;
  if (i < n4) {
    float4 v = *(const float4*)(X + (size_t)i * 4);
    f16x4 o = {(f16)v.x, (f16)v.y, (f16)v.z, (f16)v.w};
    *(f16x4*)(XH + (size_t)i * 4) = o;
  }
  if (i < ne) atomicAdd(&deg[edst[i]], 1);
}

// ---------------- CSR build (2-phase; p2 folded into p3) ----------------
// p1: per-block inclusive scan -> rowstart (local), block total -> bsum,
//     raw per-block 64-bin degree histogram -> ghist[block][bin].
__global__ __launch_bounds__(1024) void csr_p1(const int* __restrict__ deg,
                                               int* __restrict__ rowstart,
                                               int* __restrict__ bsum,
                                               int* __restrict__ ghist, int n) {
  __shared__ int wsum[16];
  __shared__ int lhist[64];
  const int tid = threadIdx.x;
  const int lane = tid & 63, w = tid >> 6;
  if (tid < 64) lhist[tid] = 0;
  __syncthreads();
  int i = blockIdx.x * 1024 + tid;
  int d = (i < n) ? deg[i] : 0;
  if (i < n) atomicAdd(&lhist[d < 63 ? d : 63], 1);
  int v = d;
#pragma unroll
  for (int off = 1; off < 64; off <<= 1) {
    int u = __shfl_up(v, off, 64);
    if (lane >= off) v += u;
  }
  if (lane == 63) wsum[w] = v;
  __syncthreads();
  if (w == 0) {
    int t = (lane < 16) ? wsum[lane] : 0;
#pragma unroll
    for (int off = 1; off < 16; off <<= 1) {
      int u = __shfl_up(t, off, 64);
      if (lane >= off) t += u;
    }
    if (lane < 16) wsum[lane] = t;
  }
  __syncthreads();
  int add = (w > 0 ? wsum[w - 1] : 0);
  if (i < n) rowstart[i + 1] = v + add;
  if (tid == 0) bsum[blockIdx.x] = wsum[15];
  if (tid < 64) ghist[blockIdx.x * 64 + tid] = lhist[tid];
}

// p3: each block redundantly recomputes the tiny cross-block scans (20x64
// values) in its first wave -- removes the old 1-block csr_p2 launch.
// Finalizes rowstart; scatters degree-bucketed perm (DESCENDING deg = LPT).
__global__ __launch_bounds__(1024) void csr_p3(const int* __restrict__ deg,
                                               int* __restrict__ rowstart,
                                               const int* __restrict__ bsum,
                                               const int* __restrict__ ghist,
                                               int* __restrict__ perm, int n, int nb) {
  __shared__ int lcur[64];
  __shared__ int base[64];
  __shared__ int radd_s;
  const int tid = threadIdx.x;
  if (tid < 64) {
    lcur[tid] = 0;
    int pre = 0, tot = 0;
    for (int b = 0; b < nb; b++) {
      int v = ghist[b * 64 + tid];
      pre += (b < (int)blockIdx.x) ? v : 0;
      tot += v;
    }
    int incl = tot;
#pragma unroll
    for (int off = 1; off < 64; off <<= 1) {
      int u = __shfl_up(incl, off, 64);
      if (tid >= off) incl += u;
    }
    base[tid] = (n - incl) + pre;  // descending bucket start + within-bin prefix
  }
  if (tid == 0) {
    int r = 0;
    for (int b = 0; b < (int)blockIdx.x; b++) r += bsum[b];
    radd_s = r;
  }
  __syncthreads();
  int i = blockIdx.x * 1024 + tid;
  if (i < n) {
    rowstart[i + 1] += radd_s;
    int d = deg[i];
    int b = d < 63 ? d : 63;
    int pos = atomicAdd(&lcur[b], 1);
    perm[base[b] + pos] = i;
  }
  if (blockIdx.x == 0 && tid == 0) rowstart[0] = 0;
}

__global__ void scatter_kernel(const int* __restrict__ src, const int* __restrict__ dstp,
                               const int* __restrict__ rowstart, int* __restrict__ cursor,
                               int* __restrict__ csr, int n) {
  int i = blockIdx.x * blockDim.x + threadIdx.x;
  if (i < n) {
    int d = dstp[i];
    int pos = atomicAdd(&cursor[d], 1);
    csr[rowstart[d] + pos] = src[i];
  }
}

// one 16-lane subgroup per row; 16-element bitonic network (deg<=16 covers
// ~99.6% of Poisson(8) rows). Ascending order == insertion sort result.
__global__ void sort_kernel(const int* __restrict__ rowstart, int* __restrict__ csr,
                            const int* __restrict__ perm, int n) {
  int idx = blockIdx.x * blockDim.x + threadIdx.x;
  int sub = idx >> 4;
  int u = idx & 15;
  if (sub >= n) return;
  int i = perm[sub];
  int a = rowstart[i], b = rowstart[i + 1];
  int d = b - a;
  if (d <= 1) return;
  if (d <= 16) {
    int v = (u < d) ? csr[a + u] : 0x7FFFFFFF;
#pragma unroll
    for (int k = 2; k <= 16; k <<= 1) {
#pragma unroll
      for (int j = 16; j > 0; j >>= 1) {
        if (j > (k >> 1)) continue;
        int o = __shfl_xor(v, j, 64);
        bool takeMin = (((u & k) == 0) == ((u & j) == 0));
        v = takeMin ? (v < o ? v : o) : (v > o ? v : o);
      }
    }
    if (u < d) csr[a + u] = v;
  } else if (u == 0) {
    for (int j = a + 1; j < b; j++) {
      int v = csr[j];
      int k = j - 1;
      while (k >= a && csr[k] > v) { csr[k + 1] = csr[k]; k--; }
      csr[k + 1] = v;
    }
  }
}

// ---------------- weights: W [128][HC] f32 -> WT [HC][128] f16 ----------------
__global__ __launch_bounds__(256) void transconv_all(
    const float* __restrict__ W0, const float* __restrict__ W1,
    const float* __restrict__ W2, const float* __restrict__ W3,
    const float* __restrict__ W4, const float* __restrict__ W5,
    f16* O0, f16* O1, f16* O2, f16* O3, f16* O4, f16* O5) {
  const float* W; f16* O; int HC;
  switch (blockIdx.z) {
    case 0: W = W0; O = O0; HC = 1024; break;
    case 1: W = W1; O = O1; HC = 1024; break;
    case 2: W = W2; O = O2; HC = 1024; break;
    case 3: W = W3; O = O3; HC = 1024; break;
    case 4: W = W4; O = O4; HC = 512; break;
    default: W = W5; O = O5; HC = 512; break;
  }
  int c0 = blockIdx.x * 32;
  if (c0 >= HC) return;
  __shared__ float t[32][33];
  int k0 = blockIdx.y * 32;
  int tx = threadIdx.x & 31, ty = threadIdx.x >> 5;  // 32 x 8
#pragma unroll
  for (int j = 0; j < 4; j++) {
    int k = k0 + ty + j * 8;
    t[ty + j * 8][tx] = W[(size_t)k * HC + c0 + tx];
  }
  __syncthreads();
#pragma unroll
  for (int j = 0; j < 4; j++) {
    int c = c0 + ty + j * 8;
    O[(size_t)c * 128 + k0 + tx] = (f16)t[tx][ty + j * 8];
  }
}

// ---------------- f16 MFMA GEMM (XCD swizzle + LDS-staged C write) ----------
template <int YB>
__global__ __launch_bounds__(256) void gemm_f16(const f16* __restrict__ A,
                                                const f16* __restrict__ BT,
                                                f16* __restrict__ C, int M, int Nout) {
  const int nx = (M + 127) / 128;
  const int chunk = nx * YB / 8;
  const int bid = blockIdx.x;
  const int p = (bid % 8) * chunk + bid / 8;
  const int bx = p / YB, by = p % YB;

  const int w = threadIdx.x >> 6, lane = threadIdx.x & 63;
  const int wm = w >> 1, wn = w & 1;
  const int row0 = bx * 128 + wm * 64;
  const int col0 = by * 128 + wn * 64;
  const int lr = lane & 15, lk = (lane >> 4) * 8;

  __shared__ f16 ct[128][144];

  f32x4 acc[4][4] = {};
  const f16* Arow[4];
  const f16* Brow[4];
#pragma unroll
  for (int m = 0; m < 4; m++) {
    int r = row0 + m * 16 + lr;
    r = r < M ? r : M - 1;
    Arow[m] = A + (size_t)r * 128 + lk;
  }
#pragma unroll
  for (int n = 0; n < 4; n++) {
    int c = col0 + n * 16 + lr;
    Brow[n] = BT + (size_t)c * 128 + lk;
  }
#pragma unroll
  for (int ks = 0; ks < 4; ks++) {
    f16x8 a[4], b[4];
#pragma unroll
    for (int m = 0; m < 4; m++) a[m] = *(const f16x8*)(Arow[m] + ks * 32);
#pragma unroll
    for (int n = 0; n < 4; n++) b[n] = *(const f16x8*)(Brow[n] + ks * 32);
#pragma unroll
    for (int m = 0; m < 4; m++)
#pragma unroll
      for (int n = 0; n < 4; n++)
        acc[m][n] = __builtin_amdgcn_mfma_f32_16x16x32_f16(a[m], b[n], acc[m][n], 0, 0, 0);
  }
  const int lrow = wm * 64, lcol = wn * 64;
#pragma unroll
  for (int m = 0; m < 4; m++) {
    int rbase = lrow + m * 16 + (lane >> 4) * 4;
#pragma unroll
    for (int r = 0; r < 4; r++) {
#pragma unroll
      for (int n = 0; n < 4; n++) {
        ct[rbase + r][lcol + n * 16 + lr] = (f16)acc[m][n][r];
      }
    }
  }
  __syncthreads();
  const int t = threadIdx.x;
  const int cidx = (t & 15) * 8;
  const int rowblk = bx * 128, colblk = by * 128;
#pragma unroll
  for (int rr = (t >> 4); rr < 128; rr += 16) {
    int gr = rowblk + rr;
    if (gr < M) {
      uint4 v = *(const uint4*)(&ct[rr][cidx]);
      *(uint4*)(C + (size_t)gr * Nout + colblk + cidx) = v;
    }
  }
}

// Layer-1 GEMM: xl half (cols 0-1023) written as fp8-e4m3 (1KB rows),
// xr half (cols 1024-2047) as f16 (stride 1024 f16).
template <int YB>
__global__ __launch_bounds__(256) void gemm_f16_split(const f16* __restrict__ A,
                                                      const f16* __restrict__ BT,
                                                      u8* __restrict__ C8,
                                                      f16* __restrict__ C16, int M) {
  const int Nout = YB * 128;
  const int nx = (M + 127) / 128;
  const int chunk = nx * YB / 8;
  const int bid = blockIdx.x;
  const int p = (bid % 8) * chunk + bid / 8;
  const int bx = p / YB, by = p % YB;

  const int w = threadIdx.x >> 6, lane = threadIdx.x & 63;
  const int wm = w >> 1, wn = w & 1;
  const int row0 = bx * 128 + wm * 64;
  const int col0 = by * 128 + wn * 64;
  const int lr = lane & 15, lk = (lane >> 4) * 8;

  __shared__ f16 ct[128][144];

  f32x4 acc[4][4] = {};
  const f16* Arow[4];
  const f16* Brow[4];
#pragma unroll
  for (int m = 0; m < 4; m++) {
    int r = row0 + m * 16 + lr;
    r = r < M ? r : M - 1;
    Arow[m] = A + (size_t)r * 128 + lk;
  }
#pragma unroll
  for (int n = 0; n < 4; n++) {
    int c = col0 + n * 16 + lr;
    Brow[n] = BT + (size_t)c * 128 + lk;
  }
#pragma unroll
  for (int ks = 0; ks < 4; ks++) {
    f16x8 a[4], b[4];
#pragma unroll
    for (int m = 0; m < 4; m++) a[m] = *(const f16x8*)(Arow[m] + ks * 32);
#pragma unroll
    for (int n = 0; n < 4; n++) b[n] = *(const f16x8*)(Brow[n] + ks * 32);
#pragma unroll
    for (int m = 0; m < 4; m++)
#pragma unroll
      for (int n = 0; n < 4; n++)
        acc[m][n] = __builtin_amdgcn_mfma_f32_16x16x32_f16(a[m], b[n], acc[m][n], 0, 0, 0);
  }
  const int lrow = wm * 64, lcol = wn * 64;
#pragma unroll
  for (int m = 0; m < 4; m++) {
    int rbase = lrow + m * 16 + (lane >> 4) * 4;
#pragma unroll
    for (int r = 0; r < 4; r++) {
#pragma unroll
      for (int n = 0; n < 4; n++) {
        ct[rbase + r][lcol + n * 16 + lr] = (f16)acc[m][n][r];
      }
    }
  }
  __syncthreads();
  const int t = threadIdx.x;
  const int cidx = (t & 15) * 8;
  const int rowblk = bx * 128, colblk = by * 128;
  if (by < YB / 2) {  // xl half -> fp8
#pragma unroll
    for (int rr = (t >> 4); rr < 128; rr += 16) {
      int gr = rowblk + rr;
      if (gr < M) {
        f16x8 v = *(const f16x8*)(&ct[rr][cidx]);
        int lo = __builtin_amdgcn_cvt_pk_fp8_f32((float)v[0], (float)v[1], 0, false);
        lo = __builtin_amdgcn_cvt_pk_fp8_f32((float)v[2], (float)v[3], lo, true);
        int hi = __builtin_amdgcn_cvt_pk_fp8_f32((float)v[4], (float)v[5], 0, false);
        hi = __builtin_amdgcn_cvt_pk_fp8_f32((float)v[6], (float)v[7], hi, true);
        uint2 o;
        o.x = (uint32)lo;
        o.y = (uint32)hi;
        *(uint2*)(C8 + (size_t)gr * 1024 + colblk + cidx) = o;
      }
    }
  } else {  // xr half -> f16, stride 1024
    const int col16 = colblk - 1024;
#pragma unroll
    for (int rr = (t >> 4); rr < 128; rr += 16) {
      int gr = rowblk + rr;
      if (gr < M) {
        uint4 v = *(const uint4*)(&ct[rr][cidx]);
        *(uint4*)(C16 + (size_t)gr * 1024 + col16 + cidx) = v;
      }
    }
  }
}

// ---------------- fused GATv2 aggregation ----------------
// NOTE (R14 lesson): persistent grid-stride agg REGRESSED; keep 1-shot blocks.
// NOTE (R11 lesson): 8-deep masked merge REGRESSED; keep 4-deep + scalar tail.
struct LV { f16x2 v[4]; };

__device__ __forceinline__ f16x2 bc2(uint32 x) { return __builtin_bit_cast(f16x2, x); }

__device__ __forceinline__ LV load8(const char* __restrict__ base, uint32 off) {
  uint4 r = *(const uint4*)(base + off);
  LV o;
  o.v[0] = bc2(r.x); o.v[1] = bc2(r.y); o.v[2] = bc2(r.z); o.v[3] = bc2(r.w);
  return o;
}

// fp8-e4m3 gather: 8 bytes -> 8 f16 (HW cvt: fp8->f32 pairs, then pkrtz; both
// conversions are exact embeddings so no extra rounding beyond fp8 storage).
__device__ __forceinline__ LV load8_f8(const char* __restrict__ base, uint32 off) {
  uint2 w = *(const uint2*)(base + off);
  auto a = __builtin_amdgcn_cvt_pk_f32_fp8((int)w.x, false);
  auto b = __builtin_amdgcn_cvt_pk_f32_fp8((int)w.x, true);
  auto c = __builtin_amdgcn_cvt_pk_f32_fp8((int)w.y, false);
  auto d = __builtin_amdgcn_cvt_pk_f32_fp8((int)w.y, true);
  LV o;
  o.v[0] = __builtin_bit_cast(f16x2, __builtin_amdgcn_cvt_pkrtz(a[0], a[1]));
  o.v[1] = __builtin_bit_cast(f16x2, __builtin_amdgcn_cvt_pkrtz(b[0], b[1]));
  o.v[2] = __builtin_bit_cast(f16x2, __builtin_amdgcn_cvt_pkrtz(c[0], c[1]));
  o.v[3] = __builtin_bit_cast(f16x2, __builtin_amdgcn_cvt_pkrtz(d[0], d[1]));
  return o;
}

template <bool F8>
__device__ __forceinline__ LV loadxl(const char* __restrict__ p, uint32 off) {
  if constexpr (F8) return load8_f8(p, off);
  else return load8(p, off);
}

__device__ __forceinline__ f16x2 leaky2(f16x2 z) {
  f16x2 zs = z * (f16)0.2f;
  return __builtin_elementwise_max(z, zs);
}

__device__ __forceinline__ float edot(const LV& x, const f16x2* xr2, const f16x2* att2) {
  float ea = 0.f, eb = 0.f;
  ea = __builtin_amdgcn_fdot2(leaky2(x.v[0] + xr2[0]), att2[0], ea, false);
  eb = __builtin_amdgcn_fdot2(leaky2(x.v[1] + xr2[1]), att2[1], eb, false);
  ea = __builtin_amdgcn_fdot2(leaky2(x.v[2] + xr2[2]), att2[2], ea, false);
  eb = __builtin_amdgcn_fdot2(leaky2(x.v[3] + xr2[3]), att2[3], eb, false);
  return ea + eb;
}

template <int PAT>
__device__ __forceinline__ float swz(float x) {
  return __int_as_float(__builtin_amdgcn_ds_swizzle(__float_as_int(x), PAT));
}

__device__ __forceinline__ void red16x4(float& a, float& b, float& c, float& d) {
  a += swz<0x041F>(a); b += swz<0x041F>(b); c += swz<0x041F>(c); d += swz<0x041F>(d);
  a += swz<0x081F>(a); b += swz<0x081F>(b); c += swz<0x081F>(c); d += swz<0x081F>(d);
  a += swz<0x101F>(a); b += swz<0x101F>(b); c += swz<0x101F>(c); d += swz<0x101F>(d);
  a += swz<0x201F>(a); b += swz<0x201F>(b); c += swz<0x201F>(c); d += swz<0x201F>(d);
}
__device__ __forceinline__ float red16(float a) {
  a += swz<0x041F>(a);
  a += swz<0x081F>(a);
  a += swz<0x101F>(a);
  a += swz<0x201F>(a);
  return a;
}

// H heads; DG dst-groups/block; F8: xl stored fp8; LGXL/LGXR: log2 row strides
// (bytes) of the xl / xr buffers (separate base pointers).
template <int H, int DG, bool RELU, bool WF32, bool F8, int LGXL, int LGXR>
__global__ __launch_bounds__(H * DG * 64) void agg_kernel(
    const f16* __restrict__ h_in, const char* __restrict__ xlp,
    const char* __restrict__ xrp, const float* __restrict__ att,
    const float* __restrict__ bias, const int* __restrict__ csr,
    const int* __restrict__ rowstart, const int* __restrict__ perm,
    float* __restrict__ h_out, f16* __restrict__ hh) {
  __shared__ float headout[H][4 * DG][DH];
  __shared__ int nodes[4 * DG];
  const int wv = threadIdx.x >> 6;
  const int h = wv & (H - 1);
  const int dg = wv / H;
  const int lane = threadIdx.x & 63;
  const int g = lane >> 4, u = lane & 15;
  const int c0 = u * 8;
  if (threadIdx.x < 4 * DG) nodes[threadIdx.x] = perm[blockIdx.x * 4 * DG + threadIdx.x];
  const int dst = perm[blockIdx.x * 4 * DG + dg * 4 + g];
  const uint32 loff_xl = (uint32)(h * DH + c0) << (F8 ? 0 : 1);
  const uint32 loff_xr = (uint32)(h * DH + c0) * 2;

  f16x2 att2[4], xr2[4];
  {
    const float* ap = att + h * DH + c0;
    float a0[8];
    *(float4*)a0 = *(const float4*)ap;
    *(float4*)(a0 + 4) = *(const float4*)(ap + 4);
#pragma unroll
    for (int q = 0; q < 4; q++) att2[q] = f16x2{(f16)a0[2 * q], (f16)a0[2 * q + 1]};
    LV xrv = load8(xrp, ((uint32)dst << LGXR) + loff_xr);
#pragma unroll
    for (int q = 0; q < 4; q++) xr2[q] = xrv.v[q];
  }

  const int js = rowstart[dst], je = rowstart[dst + 1];

  // self loop seed
  float m, s;
  f16x2 acc[4];
  {
    LV xv = loadxl<F8>(xlp, ((uint32)dst << LGXL) + loff_xl);
    m = red16(edot(xv, xr2, att2));
    s = 1.f;
#pragma unroll
    for (int q = 0; q < 4; q++) acc[q] = xv.v[q];
  }

  // 4-deep prefetch over CSR row (indices clamped to je-1)
  LV pf0, pf1, pf2, pf3;
  {
    int ja = js < je ? js : je - 1;
    int jb = js + 1 < je ? js + 1 : je - 1;
    int jc = js + 2 < je ? js + 2 : je - 1;
    int jd = js + 3 < je ? js + 3 : je - 1;
    if (js < je) {
      pf0 = loadxl<F8>(xlp, ((uint32)csr[ja] << LGXL) + loff_xl);
      pf1 = loadxl<F8>(xlp, ((uint32)csr[jb] << LGXL) + loff_xl);
      pf2 = loadxl<F8>(xlp, ((uint32)csr[jc] << LGXL) + loff_xl);
      pf3 = loadxl<F8>(xlp, ((uint32)csr[jd] << LGXL) + loff_xl);
    }
  }

  int j = js;
  for (; j + 3 < je; j += 4) {
    LV cv0 = pf0, cv1 = pf1, cv2 = pf2, cv3 = pf3;
    int ja = j + 4 < je ? j + 4 : je - 1;
    int jb = j + 5 < je ? j + 5 : je - 1;
    int jc = j + 6 < je ? j + 6 : je - 1;
    int jd = j + 7 < je ? j + 7 : je - 1;
    pf0 = loadxl<F8>(xlp, ((uint32)csr[ja] << LGXL) + loff_xl);
    pf1 = loadxl<F8>(xlp, ((uint32)csr[jb] << LGXL) + loff_xl);
    pf2 = loadxl<F8>(xlp, ((uint32)csr[jc] << LGXL) + loff_xl);
    pf3 = loadxl<F8>(xlp, ((uint32)csr[jd] << LGXL) + loff_xl);

    float e0 = edot(cv0, xr2, att2);
    float e1 = edot(cv1, xr2, att2);
    float e2 = edot(cv2, xr2, att2);
    float e3 = edot(cv3, xr2, att2);
    red16x4(e0, e1, e2, e3);

    float mn = fmaxf(fmaxf(fmaxf(m, e0), fmaxf(e1, e2)), e3);
    float a = __expf(m - mn);
    float p0 = __expf(e0 - mn);
    float p1 = __expf(e1 - mn);
    float p2 = __expf(e2 - mn);
    float p3 = __expf(e3 - mn);
    s = s * a + ((p0 + p1) + (p2 + p3));
    f16 ah = (f16)a, g0 = (f16)p0, g1 = (f16)p1, g2 = (f16)p2, g3 = (f16)p3;
    f16x2 a2 = {ah, ah}, q0 = {g0, g0}, q1 = {g1, g1}, q2 = {g2, g2}, q3 = {g3, g3};
#pragma unroll
    for (int q = 0; q < 4; q++) {
      f16x2 t = acc[q] * a2;
      t = cv0.v[q] * q0 + t;
      t = cv1.v[q] * q1 + t;
      t = cv2.v[q] * q2 + t;
      t = cv3.v[q] * q3 + t;
      acc[q] = t;
    }
    m = mn;
  }
  // tail: consume remaining prefetched edges one at a time
  for (int t = 0; j < je; j++, t++) {
    LV cv = (t == 0) ? pf0 : (t == 1) ? pf1 : pf2;
    float e = red16(edot(cv, xr2, att2));
    float mn = fmaxf(m, e);
    float a = __expf(m - mn);
    float p = __expf(e - mn);
    s = s * a + p;
    f16 ah = (f16)a, gh = (f16)p;
    f16x2 a2 = {ah, ah}, p2 = {gh, gh};
#pragma unroll
    for (int q = 0; q < 4; q++) acc[q] = acc[q] * a2 + cv.v[q] * p2;
    m = mn;
  }

  float inv = 1.f / s;
#pragma unroll
  for (int q = 0; q < 4; q++) {
    headout[h][dg * 4 + g][c0 + 2 * q] = (float)acc[q][0] * inv;
    headout[h][dg * 4 + g][c0 + 2 * q + 1] = (float)acc[q][1] * inv;
  }
  __syncthreads();
  for (int t = threadIdx.x; t < 4 * DG * DH; t += H * DG * 64) {
    int d = t >> 7, c = t & 127;
    float sum = 0.f;
#pragma unroll
    for (int q = 0; q < H; q++) sum += headout[q][d][c];
    float r = sum * (1.f / H) + bias[c];
    if (RELU) r = fmaxf(r, 0.f);
    int node = nodes[d];
    float o = r + (float)h_in[(size_t)node * DH + c];
    if (WF32) h_out[(size_t)node * DH + c] = o;
    else hh[(size_t)node * DH + c] = (f16)o;
  }
}

extern "C" void kernel_launch(void* const* d_in, const int* in_sizes, int n_in,
                              void* d_out, int out_size, void* d_ws, size_t ws_size,
                              hipStream_t stream) {
  const float* x = (const float*)d_in[0];
  const int* ei = (const int*)d_in[1];
  const float* Wl1 = (const float*)d_in[2];
  const float* Wr1 = (const float*)d_in[3];
  const float* att1 = (const float*)d_in[4];
  const float* b1 = (const float*)d_in[5];
  const float* Wl2 = (const float*)d_in[6];
  const float* Wr2 = (const float*)d_in[7];
  const float* att2 = (const float*)d_in[8];
  const float* b2 = (const float*)d_in[9];
  const float* Wl3 = (const float*)d_in[10];
  const float* Wr3 = (const float*)d_in[11];
  const float* att3 = (const float*)d_in[12];
  const float* b3 = (const float*)d_in[13];
  float* out = (float*)d_out;

  char* p = (char*)d_ws;
  f16* xlr = (f16*)p; p += (size_t)NN * 2048 * 2;
  u8* xl8  = (u8*)p;  p += (size_t)NN * 1024;
  f16* xh  = (f16*)p; p += (size_t)NN * DH * 2;
  f16* h1h = (f16*)p; p += (size_t)NN * DH * 2;
  f16* h2h = (f16*)p; p += (size_t)NN * DH * 2;
  f16* WT1 = (f16*)p; p += (size_t)2048 * 128 * 2;
  f16* WT2 = (f16*)p; p += (size_t)2048 * 128 * 2;
  f16* WT3 = (f16*)p; p += (size_t)1024 * 128 * 2;
  int* deg      = (int*)p; p += (size_t)NN * 4;
  int* cursor   = (int*)p; p += (size_t)NN * 4;
  int* rowstart = (int*)p; p += (size_t)(NN + 1) * 4;
  int* perm     = (int*)p; p += (size_t)NN * 4;
  int* bsum     = (int*)p; p += (size_t)32 * 4;
  int* ghist    = (int*)p; p += (size_t)20 * 64 * 4;
  int* csr      = (int*)p;

  const int* esrc = ei;
  const int* edst = ei + NE;

  const int nbc = (NN + 1023) / 1024;  // 20 CSR-build blocks

  hipMemsetAsync(deg, 0, sizeof(int) * 2 * NN, stream);  // deg + cursor
  conv_count_kernel<<<(NN * DH / 4 + 255) / 256, 256, 0, stream>>>(
      x, xh, NN * DH / 4, edst, deg, NE);
  csr_p1<<<nbc, 1024, 0, stream>>>(deg, rowstart, bsum, ghist, NN);
  csr_p3<<<nbc, 1024, 0, stream>>>(deg, rowstart, bsum, ghist, perm, NN, nbc);
  scatter_kernel<<<(NE + 255) / 256, 256, 0, stream>>>(esrc, edst, rowstart, cursor, csr, NE);
  sort_kernel<<<(NN * 16 + 255) / 256, 256, 0, stream>>>(rowstart, csr, perm, NN);
  transconv_all<<<dim3(32, 4, 6), 256, 0, stream>>>(
      Wl1, Wr1, Wl2, Wr2, Wl3, Wr3,
      WT1, WT1 + (size_t)1024 * 128, WT2, WT2 + (size_t)1024 * 128,
      WT3, WT3 + (size_t)512 * 128);

  const int nx = (NN + 127) / 128;  // 157

  // layer 1: xl fp8 (gathered), xr f16 (streamed)
  gemm_f16_split<16><<<nx * 16, 256, 0, stream>>>(xh, WT1, xl8, xlr, NN);
  agg_kernel<8, 1, true, false, true, 10, 11><<<NN / 4, 512, 0, stream>>>(
      xh, (const char*)xl8, (const char*)xlr, att1, b1, csr, rowstart, perm,
      nullptr, h1h);
  // layer 2: f16 interleaved (stride 4096 B; xr at +2048 B)
  gemm_f16<16><<<nx * 16, 256, 0, stream>>>(h1h, WT2, xlr, NN, 2048);
  agg_kernel<8, 1, true, false, false, 12, 12><<<NN / 4, 512, 0, stream>>>(
      h1h, (const char*)xlr, (const char*)xlr + 2048, att2, b2, csr, rowstart,
      perm, nullptr, h2h);
  // layer 3: f16 (stride 2048 B; xr at +1024 B)
  gemm_f16<8><<<nx * 8, 256, 0, stream>>>(h2h, WT3, xlr, NN, 1024);
  agg_kernel<4, 2, false, true, false, 11, 11><<<NN / 8, 512, 0, stream>>>(
      h2h, (const char*)xlr, (const char*)xlr + 1024, att3, b3, csr, rowstart,
      perm, out, nullptr);
}

// Round 17
// 296.690 us; speedup vs baseline: 1.1857x; 1.0517x over previous
//
#include <hip/hip_runtime.h>
#include <math.h>

#define NN 20000
#define NE 160000
#define DH 128

typedef _Float16 f16;
typedef f16 f16x2 __attribute__((ext_vector_type(2)));
typedef f16 f16x4 __attribute__((ext_vector_type(4)));
typedef f16 f16x8 __attribute__((ext_vector_type(8)));
typedef float f32x4 __attribute__((ext_vector_type(4)));
typedef unsigned int uint32;
typedef unsigned char u8;

// ---------------- prep: fused x->f16 convert + degree count ----------------
__global__ void conv_count_kernel(const float* __restrict__ X, f16* __restrict__ XH,
                                  int n4, const int* __restrict__ edst,
                                  int* __restrict__ deg, int ne) {
  int i = blockIdx.x * blockDim.x + threadIdx.x;
  if (i < n4) {
    float4 v = *(const float4*)(X + (size_t)i * 4);
    f16x4 o = {(f16)v.x, (f16)v.y, (f16)v.z, (f16)v.w};
    *(f16x4*)(XH + (size_t)i * 4) = o;
  }
  if (i < ne) atomicAdd(&deg[edst[i]], 1);
}

// ---------------- CSR build (2-phase; p2 folded into p3) ----------------
__global__ __launch_bounds__(1024) void csr_p1(const int* __restrict__ deg,
                                               int* __restrict__ rowstart,
                                               int* __restrict__ bsum,
                                               int* __restrict__ ghist, int n) {
  __shared__ int wsum[16];
  __shared__ int lhist[64];
  const int tid = threadIdx.x;
  const int lane = tid & 63, w = tid >> 6;
  if (tid < 64) lhist[tid] = 0;
  __syncthreads();
  int i = blockIdx.x * 1024 + tid;
  int d = (i < n) ? deg[i] : 0;
  if (i < n) atomicAdd(&lhist[d < 63 ? d : 63], 1);
  int v = d;
#pragma unroll
  for (int off = 1; off < 64; off <<= 1) {
    int u = __shfl_up(v, off, 64);
    if (lane >= off) v += u;
  }
  if (lane == 63) wsum[w] = v;
  __syncthreads();
  if (w == 0) {
    int t = (lane < 16) ? wsum[lane] : 0;
#pragma unroll
    for (int off = 1; off < 16; off <<= 1) {
      int u = __shfl_up(t, off, 64);
      if (lane >= off) t += u;
    }
    if (lane < 16) wsum[lane] = t;
  }
  __syncthreads();
  int add = (w > 0 ? wsum[w - 1] : 0);
  if (i < n) rowstart[i + 1] = v + add;
  if (tid == 0) bsum[blockIdx.x] = wsum[15];
  if (tid < 64) ghist[blockIdx.x * 64 + tid] = lhist[tid];
}

// p3: each block redundantly recomputes the tiny cross-block scans (20x64).
__global__ __launch_bounds__(1024) void csr_p3(const int* __restrict__ deg,
                                               int* __restrict__ rowstart,
                                               const int* __restrict__ bsum,
                                               const int* __restrict__ ghist,
                                               int* __restrict__ perm, int n, int nb) {
  __shared__ int lcur[64];
  __shared__ int base[64];
  __shared__ int radd_s;
  const int tid = threadIdx.x;
  if (tid < 64) {
    lcur[tid] = 0;
    int pre = 0, tot = 0;
    for (int b = 0; b < nb; b++) {
      int v = ghist[b * 64 + tid];
      pre += (b < (int)blockIdx.x) ? v : 0;
      tot += v;
    }
    int incl = tot;
#pragma unroll
    for (int off = 1; off < 64; off <<= 1) {
      int u = __shfl_up(incl, off, 64);
      if (tid >= off) incl += u;
    }
    base[tid] = (n - incl) + pre;  // descending bucket start + within-bin prefix
  }
  if (tid == 0) {
    int r = 0;
    for (int b = 0; b < (int)blockIdx.x; b++) r += bsum[b];
    radd_s = r;
  }
  __syncthreads();
  int i = blockIdx.x * 1024 + tid;
  if (i < n) {
    rowstart[i + 1] += radd_s;
    int d = deg[i];
    int b = d < 63 ? d : 63;
    int pos = atomicAdd(&lcur[b], 1);
    perm[base[b] + pos] = i;
  }
  if (blockIdx.x == 0 && tid == 0) rowstart[0] = 0;
}

__global__ void scatter_kernel(const int* __restrict__ src, const int* __restrict__ dstp,
                               const int* __restrict__ rowstart, int* __restrict__ cursor,
                               int* __restrict__ csr, int n) {
  int i = blockIdx.x * blockDim.x + threadIdx.x;
  if (i < n) {
    int d = dstp[i];
    int pos = atomicAdd(&cursor[d], 1);
    csr[rowstart[d] + pos] = src[i];
  }
}

// one 16-lane subgroup per row; 16-element bitonic network.
__global__ void sort_kernel(const int* __restrict__ rowstart, int* __restrict__ csr,
                            const int* __restrict__ perm, int n) {
  int idx = blockIdx.x * blockDim.x + threadIdx.x;
  int sub = idx >> 4;
  int u = idx & 15;
  if (sub >= n) return;
  int i = perm[sub];
  int a = rowstart[i], b = rowstart[i + 1];
  int d = b - a;
  if (d <= 1) return;
  if (d <= 16) {
    int v = (u < d) ? csr[a + u] : 0x7FFFFFFF;
#pragma unroll
    for (int k = 2; k <= 16; k <<= 1) {
#pragma unroll
      for (int j = 16; j > 0; j >>= 1) {
        if (j > (k >> 1)) continue;
        int o = __shfl_xor(v, j, 64);
        bool takeMin = (((u & k) == 0) == ((u & j) == 0));
        v = takeMin ? (v < o ? v : o) : (v > o ? v : o);
      }
    }
    if (u < d) csr[a + u] = v;
  } else if (u == 0) {
    for (int j = a + 1; j < b; j++) {
      int v = csr[j];
      int k = j - 1;
      while (k >= a && csr[k] > v) { csr[k + 1] = csr[k]; k--; }
      csr[k + 1] = v;
    }
  }
}

// ---------------- weights: W [128][HC] f32 -> WT [HC][128] f16 ----------------
__global__ __launch_bounds__(256) void transconv_all(
    const float* __restrict__ W0, const float* __restrict__ W1,
    const float* __restrict__ W2, const float* __restrict__ W3,
    const float* __restrict__ W4, const float* __restrict__ W5,
    f16* O0, f16* O1, f16* O2, f16* O3, f16* O4, f16* O5) {
  const float* W; f16* O; int HC;
  switch (blockIdx.z) {
    case 0: W = W0; O = O0; HC = 1024; break;
    case 1: W = W1; O = O1; HC = 1024; break;
    case 2: W = W2; O = O2; HC = 1024; break;
    case 3: W = W3; O = O3; HC = 1024; break;
    case 4: W = W4; O = O4; HC = 512; break;
    default: W = W5; O = O5; HC = 512; break;
  }
  int c0 = blockIdx.x * 32;
  if (c0 >= HC) return;
  __shared__ float t[32][33];
  int k0 = blockIdx.y * 32;
  int tx = threadIdx.x & 31, ty = threadIdx.x >> 5;  // 32 x 8
#pragma unroll
  for (int j = 0; j < 4; j++) {
    int k = k0 + ty + j * 8;
    t[ty + j * 8][tx] = W[(size_t)k * HC + c0 + tx];
  }
  __syncthreads();
#pragma unroll
  for (int j = 0; j < 4; j++) {
    int c = c0 + ty + j * 8;
    O[(size_t)c * 128 + k0 + tx] = (f16)t[tx][ty + j * 8];
  }
}

// ---------------- f16 MFMA GEMM (XCD swizzle + LDS-staged C write) ----------
template <int YB>
__global__ __launch_bounds__(256) void gemm_f16(const f16* __restrict__ A,
                                                const f16* __restrict__ BT,
                                                f16* __restrict__ C, int M, int Nout) {
  const int nx = (M + 127) / 128;
  const int chunk = nx * YB / 8;
  const int bid = blockIdx.x;
  const int p = (bid % 8) * chunk + bid / 8;
  const int bx = p / YB, by = p % YB;

  const int w = threadIdx.x >> 6, lane = threadIdx.x & 63;
  const int wm = w >> 1, wn = w & 1;
  const int row0 = bx * 128 + wm * 64;
  const int col0 = by * 128 + wn * 64;
  const int lr = lane & 15, lk = (lane >> 4) * 8;

  __shared__ f16 ct[128][144];

  f32x4 acc[4][4] = {};
  const f16* Arow[4];
  const f16* Brow[4];
#pragma unroll
  for (int m = 0; m < 4; m++) {
    int r = row0 + m * 16 + lr;
    r = r < M ? r : M - 1;
    Arow[m] = A + (size_t)r * 128 + lk;
  }
#pragma unroll
  for (int n = 0; n < 4; n++) {
    int c = col0 + n * 16 + lr;
    Brow[n] = BT + (size_t)c * 128 + lk;
  }
#pragma unroll
  for (int ks = 0; ks < 4; ks++) {
    f16x8 a[4], b[4];
#pragma unroll
    for (int m = 0; m < 4; m++) a[m] = *(const f16x8*)(Arow[m] + ks * 32);
#pragma unroll
    for (int n = 0; n < 4; n++) b[n] = *(const f16x8*)(Brow[n] + ks * 32);
#pragma unroll
    for (int m = 0; m < 4; m++)
#pragma unroll
      for (int n = 0; n < 4; n++)
        acc[m][n] = __builtin_amdgcn_mfma_f32_16x16x32_f16(a[m], b[n], acc[m][n], 0, 0, 0);
  }
  const int lrow = wm * 64, lcol = wn * 64;
#pragma unroll
  for (int m = 0; m < 4; m++) {
    int rbase = lrow + m * 16 + (lane >> 4) * 4;
#pragma unroll
    for (int r = 0; r < 4; r++) {
#pragma unroll
      for (int n = 0; n < 4; n++) {
        ct[rbase + r][lcol + n * 16 + lr] = (f16)acc[m][n][r];
      }
    }
  }
  __syncthreads();
  const int t = threadIdx.x;
  const int cidx = (t & 15) * 8;
  const int rowblk = bx * 128, colblk = by * 128;
#pragma unroll
  for (int rr = (t >> 4); rr < 128; rr += 16) {
    int gr = rowblk + rr;
    if (gr < M) {
      uint4 v = *(const uint4*)(&ct[rr][cidx]);
      *(uint4*)(C + (size_t)gr * Nout + colblk + cidx) = v;
    }
  }
}

// Split GEMM (layers 1-2): xl half (cols 0..YB*64-1) written fp8-e4m3 (1KB
// rows), xr half written f16 (stride 1024 f16).
template <int YB>
__global__ __launch_bounds__(256) void gemm_f16_split(const f16* __restrict__ A,
                                                      const f16* __restrict__ BT,
                                                      u8* __restrict__ C8,
                                                      f16* __restrict__ C16, int M) {
  const int nx = (M + 127) / 128;
  const int chunk = nx * YB / 8;
  const int bid = blockIdx.x;
  const int p = (bid % 8) * chunk + bid / 8;
  const int bx = p / YB, by = p % YB;

  const int w = threadIdx.x >> 6, lane = threadIdx.x & 63;
  const int wm = w >> 1, wn = w & 1;
  const int row0 = bx * 128 + wm * 64;
  const int col0 = by * 128 + wn * 64;
  const int lr = lane & 15, lk = (lane >> 4) * 8;

  __shared__ f16 ct[128][144];

  f32x4 acc[4][4] = {};
  const f16* Arow[4];
  const f16* Brow[4];
#pragma unroll
  for (int m = 0; m < 4; m++) {
    int r = row0 + m * 16 + lr;
    r = r < M ? r : M - 1;
    Arow[m] = A + (size_t)r * 128 + lk;
  }
#pragma unroll
  for (int n = 0; n < 4; n++) {
    int c = col0 + n * 16 + lr;
    Brow[n] = BT + (size_t)c * 128 + lk;
  }
#pragma unroll
  for (int ks = 0; ks < 4; ks++) {
    f16x8 a[4], b[4];
#pragma unroll
    for (int m = 0; m < 4; m++) a[m] = *(const f16x8*)(Arow[m] + ks * 32);
#pragma unroll
    for (int n = 0; n < 4; n++) b[n] = *(const f16x8*)(Brow[n] + ks * 32);
#pragma unroll
    for (int m = 0; m < 4; m++)
#pragma unroll
      for (int n = 0; n < 4; n++)
        acc[m][n] = __builtin_amdgcn_mfma_f32_16x16x32_f16(a[m], b[n], acc[m][n], 0, 0, 0);
  }
  const int lrow = wm * 64, lcol = wn * 64;
#pragma unroll
  for (int m = 0; m < 4; m++) {
    int rbase = lrow + m * 16 + (lane >> 4) * 4;
#pragma unroll
    for (int r = 0; r < 4; r++) {
#pragma unroll
      for (int n = 0; n < 4; n++) {
        ct[rbase + r][lcol + n * 16 + lr] = (f16)acc[m][n][r];
      }
    }
  }
  __syncthreads();
  const int t = threadIdx.x;
  const int cidx = (t & 15) * 8;
  const int rowblk = bx * 128, colblk = by * 128;
  if (by < YB / 2) {  // xl half -> fp8
#pragma unroll
    for (int rr = (t >> 4); rr < 128; rr += 16) {
      int gr = rowblk + rr;
      if (gr < M) {
        f16x8 v = *(const f16x8*)(&ct[rr][cidx]);
        int lo = __builtin_amdgcn_cvt_pk_fp8_f32((float)v[0], (float)v[1], 0, false);
        lo = __builtin_amdgcn_cvt_pk_fp8_f32((float)v[2], (float)v[3], lo, true);
        int hi = __builtin_amdgcn_cvt_pk_fp8_f32((float)v[4], (float)v[5], 0, false);
        hi = __builtin_amdgcn_cvt_pk_fp8_f32((float)v[6], (float)v[7], hi, true);
        uint2 o;
        o.x = (uint32)lo;
        o.y = (uint32)hi;
        *(uint2*)(C8 + (size_t)gr * 1024 + colblk + cidx) = o;
      }
    }
  } else {  // xr half -> f16, stride 1024
    const int col16 = colblk - 1024;
#pragma unroll
    for (int rr = (t >> 4); rr < 128; rr += 16) {
      int gr = rowblk + rr;
      if (gr < M) {
        uint4 v = *(const uint4*)(&ct[rr][cidx]);
        *(uint4*)(C16 + (size_t)gr * 1024 + col16 + cidx) = v;
      }
    }
  }
}

// ---------------- fused GATv2 aggregation ----------------
// NOTE (R14): persistent grid-stride agg REGRESSED; keep 1-shot blocks.
// NOTE (R11): 8-deep masked merge REGRESSED; keep 4-deep + scalar tail.
struct LV { f16x2 v[4]; };

__device__ __forceinline__ f16x2 bc2(uint32 x) { return __builtin_bit_cast(f16x2, x); }

__device__ __forceinline__ LV load8(const char* __restrict__ base, uint32 off) {
  uint4 r = *(const uint4*)(base + off);
  LV o;
  o.v[0] = bc2(r.x); o.v[1] = bc2(r.y); o.v[2] = bc2(r.z); o.v[3] = bc2(r.w);
  return o;
}

// fp8-e4m3 gather: 8 bytes -> 8 f16 via HW cvt (exact embeddings).
__device__ __forceinline__ LV load8_f8(const char* __restrict__ base, uint32 off) {
  uint2 w = *(const uint2*)(base + off);
  auto a = __builtin_amdgcn_cvt_pk_f32_fp8((int)w.x, false);
  auto b = __builtin_amdgcn_cvt_pk_f32_fp8((int)w.x, true);
  auto c = __builtin_amdgcn_cvt_pk_f32_fp8((int)w.y, false);
  auto d = __builtin_amdgcn_cvt_pk_f32_fp8((int)w.y, true);
  LV o;
  o.v[0] = __builtin_bit_cast(f16x2, __builtin_amdgcn_cvt_pkrtz(a[0], a[1]));
  o.v[1] = __builtin_bit_cast(f16x2, __builtin_amdgcn_cvt_pkrtz(b[0], b[1]));
  o.v[2] = __builtin_bit_cast(f16x2, __builtin_amdgcn_cvt_pkrtz(c[0], c[1]));
  o.v[3] = __builtin_bit_cast(f16x2, __builtin_amdgcn_cvt_pkrtz(d[0], d[1]));
  return o;
}

template <bool F8>
__device__ __forceinline__ LV loadxl(const char* __restrict__ p, uint32 off) {
  if constexpr (F8) return load8_f8(p, off);
  else return load8(p, off);
}

__device__ __forceinline__ f16x2 leaky2(f16x2 z) {
  f16x2 zs = z * (f16)0.2f;
  return __builtin_elementwise_max(z, zs);
}

__device__ __forceinline__ float edot(const LV& x, const f16x2* xr2, const f16x2* att2) {
  float ea = 0.f, eb = 0.f;
  ea = __builtin_amdgcn_fdot2(leaky2(x.v[0] + xr2[0]), att2[0], ea, false);
  eb = __builtin_amdgcn_fdot2(leaky2(x.v[1] + xr2[1]), att2[1], eb, false);
  ea = __builtin_amdgcn_fdot2(leaky2(x.v[2] + xr2[2]), att2[2], ea, false);
  eb = __builtin_amdgcn_fdot2(leaky2(x.v[3] + xr2[3]), att2[3], eb, false);
  return ea + eb;
}

template <int PAT>
__device__ __forceinline__ float swz(float x) {
  return __int_as_float(__builtin_amdgcn_ds_swizzle(__float_as_int(x), PAT));
}

__device__ __forceinline__ void red16x4(float& a, float& b, float& c, float& d) {
  a += swz<0x041F>(a); b += swz<0x041F>(b); c += swz<0x041F>(c); d += swz<0x041F>(d);
  a += swz<0x081F>(a); b += swz<0x081F>(b); c += swz<0x081F>(c); d += swz<0x081F>(d);
  a += swz<0x101F>(a); b += swz<0x101F>(b); c += swz<0x101F>(c); d += swz<0x101F>(d);
  a += swz<0x201F>(a); b += swz<0x201F>(b); c += swz<0x201F>(c); d += swz<0x201F>(d);
}
__device__ __forceinline__ float red16(float a) {
  a += swz<0x041F>(a);
  a += swz<0x081F>(a);
  a += swz<0x101F>(a);
  a += swz<0x201F>(a);
  return a;
}

// H heads; DG dst-groups/block; F8: xl stored fp8; LGXL/LGXR: log2 row strides.
template <int H, int DG, bool RELU, bool WF32, bool F8, int LGXL, int LGXR>
__global__ __launch_bounds__(H * DG * 64) void agg_kernel(
    const f16* __restrict__ h_in, const char* __restrict__ xlp,
    const char* __restrict__ xrp, const float* __restrict__ att,
    const float* __restrict__ bias, const int* __restrict__ csr,
    const int* __restrict__ rowstart, const int* __restrict__ perm,
    float* __restrict__ h_out, f16* __restrict__ hh) {
  __shared__ float headout[H][4 * DG][DH];
  __shared__ int nodes[4 * DG];
  const int wv = threadIdx.x >> 6;
  const int h = wv & (H - 1);
  const int dg = wv / H;
  const int lane = threadIdx.x & 63;
  const int g = lane >> 4, u = lane & 15;
  const int c0 = u * 8;
  if (threadIdx.x < 4 * DG) nodes[threadIdx.x] = perm[blockIdx.x * 4 * DG + threadIdx.x];
  const int dst = perm[blockIdx.x * 4 * DG + dg * 4 + g];
  const uint32 loff_xl = (uint32)(h * DH + c0) << (F8 ? 0 : 1);
  const uint32 loff_xr = (uint32)(h * DH + c0) * 2;

  f16x2 att2[4], xr2[4];
  {
    const float* ap = att + h * DH + c0;
    float a0[8];
    *(float4*)a0 = *(const float4*)ap;
    *(float4*)(a0 + 4) = *(const float4*)(ap + 4);
#pragma unroll
    for (int q = 0; q < 4; q++) att2[q] = f16x2{(f16)a0[2 * q], (f16)a0[2 * q + 1]};
    LV xrv = load8(xrp, ((uint32)dst << LGXR) + loff_xr);
#pragma unroll
    for (int q = 0; q < 4; q++) xr2[q] = xrv.v[q];
  }

  const int js = rowstart[dst], je = rowstart[dst + 1];

  // self loop seed
  float m, s;
  f16x2 acc[4];
  {
    LV xv = loadxl<F8>(xlp, ((uint32)dst << LGXL) + loff_xl);
    m = red16(edot(xv, xr2, att2));
    s = 1.f;
#pragma unroll
    for (int q = 0; q < 4; q++) acc[q] = xv.v[q];
  }

  // 4-deep prefetch over CSR row (indices clamped to je-1)
  LV pf0, pf1, pf2, pf3;
  {
    int ja = js < je ? js : je - 1;
    int jb = js + 1 < je ? js + 1 : je - 1;
    int jc = js + 2 < je ? js + 2 : je - 1;
    int jd = js + 3 < je ? js + 3 : je - 1;
    if (js < je) {
      pf0 = loadxl<F8>(xlp, ((uint32)csr[ja] << LGXL) + loff_xl);
      pf1 = loadxl<F8>(xlp, ((uint32)csr[jb] << LGXL) + loff_xl);
      pf2 = loadxl<F8>(xlp, ((uint32)csr[jc] << LGXL) + loff_xl);
      pf3 = loadxl<F8>(xlp, ((uint32)csr[jd] << LGXL) + loff_xl);
    }
  }

  int j = js;
  for (; j + 3 < je; j += 4) {
    LV cv0 = pf0, cv1 = pf1, cv2 = pf2, cv3 = pf3;
    int ja = j + 4 < je ? j + 4 : je - 1;
    int jb = j + 5 < je ? j + 5 : je - 1;
    int jc = j + 6 < je ? j + 6 : je - 1;
    int jd = j + 7 < je ? j + 7 : je - 1;
    pf0 = loadxl<F8>(xlp, ((uint32)csr[ja] << LGXL) + loff_xl);
    pf1 = loadxl<F8>(xlp, ((uint32)csr[jb] << LGXL) + loff_xl);
    pf2 = loadxl<F8>(xlp, ((uint32)csr[jc] << LGXL) + loff_xl);
    pf3 = loadxl<F8>(xlp, ((uint32)csr[jd] << LGXL) + loff_xl);

    float e0 = edot(cv0, xr2, att2);
    float e1 = edot(cv1, xr2, att2);
    float e2 = edot(cv2, xr2, att2);
    float e3 = edot(cv3, xr2, att2);
    red16x4(e0, e1, e2, e3);

    float mn = fmaxf(fmaxf(fmaxf(m, e0), fmaxf(e1, e2)), e3);
    float a = __expf(m - mn);
    float p0 = __expf(e0 - mn);
    float p1 = __expf(e1 - mn);
    float p2 = __expf(e2 - mn);
    float p3 = __expf(e3 - mn);
    s = s * a + ((p0 + p1) + (p2 + p3));
    f16 ah = (f16)a, g0 = (f16)p0, g1 = (f16)p1, g2 = (f16)p2, g3 = (f16)p3;
    f16x2 a2 = {ah, ah}, q0 = {g0, g0}, q1 = {g1, g1}, q2 = {g2, g2}, q3 = {g3, g3};
#pragma unroll
    for (int q = 0; q < 4; q++) {
      f16x2 t = acc[q] * a2;
      t = cv0.v[q] * q0 + t;
      t = cv1.v[q] * q1 + t;
      t = cv2.v[q] * q2 + t;
      t = cv3.v[q] * q3 + t;
      acc[q] = t;
    }
    m = mn;
  }
  // tail: consume remaining prefetched edges one at a time
  for (int t = 0; j < je; j++, t++) {
    LV cv = (t == 0) ? pf0 : (t == 1) ? pf1 : pf2;
    float e = red16(edot(cv, xr2, att2));
    float mn = fmaxf(m, e);
    float a = __expf(m - mn);
    float p = __expf(e - mn);
    s = s * a + p;
    f16 ah = (f16)a, gh = (f16)p;
    f16x2 a2 = {ah, ah}, p2 = {gh, gh};
#pragma unroll
    for (int q = 0; q < 4; q++) acc[q] = acc[q] * a2 + cv.v[q] * p2;
    m = mn;
  }

  float inv = 1.f / s;
#pragma unroll
  for (int q = 0; q < 4; q++) {
    headout[h][dg * 4 + g][c0 + 2 * q] = (float)acc[q][0] * inv;
    headout[h][dg * 4 + g][c0 + 2 * q + 1] = (float)acc[q][1] * inv;
  }
  __syncthreads();
  for (int t = threadIdx.x; t < 4 * DG * DH; t += H * DG * 64) {
    int d = t >> 7, c = t & 127;
    float sum = 0.f;
#pragma unroll
    for (int q = 0; q < H; q++) sum += headout[q][d][c];
    float r = sum * (1.f / H) + bias[c];
    if (RELU) r = fmaxf(r, 0.f);
    int node = nodes[d];
    float o = r + (float)h_in[(size_t)node * DH + c];
    if (WF32) h_out[(size_t)node * DH + c] = o;
    else hh[(size_t)node * DH + c] = (f16)o;
  }
}

extern "C" void kernel_launch(void* const* d_in, const int* in_sizes, int n_in,
                              void* d_out, int out_size, void* d_ws, size_t ws_size,
                              hipStream_t stream) {
  const float* x = (const float*)d_in[0];
  const int* ei = (const int*)d_in[1];
  const float* Wl1 = (const float*)d_in[2];
  const float* Wr1 = (const float*)d_in[3];
  const float* att1 = (const float*)d_in[4];
  const float* b1 = (const float*)d_in[5];
  const float* Wl2 = (const float*)d_in[6];
  const float* Wr2 = (const float*)d_in[7];
  const float* att2 = (const float*)d_in[8];
  const float* b2 = (const float*)d_in[9];
  const float* Wl3 = (const float*)d_in[10];
  const float* Wr3 = (const float*)d_in[11];
  const float* att3 = (const float*)d_in[12];
  const float* b3 = (const float*)d_in[13];
  float* out = (float*)d_out;

  char* p = (char*)d_ws;
  f16* xlr = (f16*)p; p += (size_t)NN * 2048 * 2;
  u8* xl8  = (u8*)p;  p += (size_t)NN * 1024;
  f16* xh  = (f16*)p; p += (size_t)NN * DH * 2;
  f16* h1h = (f16*)p; p += (size_t)NN * DH * 2;
  f16* h2h = (f16*)p; p += (size_t)NN * DH * 2;
  f16* WT1 = (f16*)p; p += (size_t)2048 * 128 * 2;
  f16* WT2 = (f16*)p; p += (size_t)2048 * 128 * 2;
  f16* WT3 = (f16*)p; p += (size_t)1024 * 128 * 2;
  int* deg      = (int*)p; p += (size_t)NN * 4;
  int* cursor   = (int*)p; p += (size_t)NN * 4;
  int* rowstart = (int*)p; p += (size_t)(NN + 1) * 4;
  int* perm     = (int*)p; p += (size_t)NN * 4;
  int* bsum     = (int*)p; p += (size_t)32 * 4;
  int* ghist    = (int*)p; p += (size_t)20 * 64 * 4;
  int* csr      = (int*)p;

  const int* esrc = ei;
  const int* edst = ei + NE;

  const int nbc = (NN + 1023) / 1024;  // 20 CSR-build blocks

  hipMemsetAsync(deg, 0, sizeof(int) * 2 * NN, stream);  // deg + cursor
  conv_count_kernel<<<(NN * DH / 4 + 255) / 256, 256, 0, stream>>>(
      x, xh, NN * DH / 4, edst, deg, NE);
  csr_p1<<<nbc, 1024, 0, stream>>>(deg, rowstart, bsum, ghist, NN);
  csr_p3<<<nbc, 1024, 0, stream>>>(deg, rowstart, bsum, ghist, perm, NN, nbc);
  scatter_kernel<<<(NE + 255) / 256, 256, 0, stream>>>(esrc, edst, rowstart, cursor, csr, NE);
  sort_kernel<<<(NN * 16 + 255) / 256, 256, 0, stream>>>(rowstart, csr, perm, NN);
  transconv_all<<<dim3(32, 4, 6), 256, 0, stream>>>(
      Wl1, Wr1, Wl2, Wr2, Wl3, Wr3,
      WT1, WT1 + (size_t)1024 * 128, WT2, WT2 + (size_t)1024 * 128,
      WT3, WT3 + (size_t)512 * 128);

  const int nx = (NN + 127) / 128;  // 157

  // layer 1: xl fp8 (gathered), xr f16 (streamed)
  gemm_f16_split<16><<<nx * 16, 256, 0, stream>>>(xh, WT1, xl8, xlr, NN);
  agg_kernel<8, 1, true, false, true, 10, 11><<<NN / 4, 512, 0, stream>>>(
      xh, (const char*)xl8, (const char*)xlr, att1, b1, csr, rowstart, perm,
      nullptr, h1h);
  // layer 2: same fp8-xl scheme (buffers reused; layer-1 agg complete)
  gemm_f16_split<16><<<nx * 16, 256, 0, stream>>>(h1h, WT2, xl8, xlr, NN);
  agg_kernel<8, 1, true, false, true, 10, 11><<<NN / 4, 512, 0, stream>>>(
      h1h, (const char*)xl8, (const char*)xlr, att2, b2, csr, rowstart, perm,
      nullptr, h2h);
  // layer 3: f16 (stride 2048 B; xr at +1024 B)
  gemm_f16<8><<<nx * 8, 256, 0, stream>>>(h2h, WT3, xlr, NN, 1024);
  agg_kernel<4, 2, false, true, false, 11, 11><<<NN / 8, 512, 0, stream>>>(
      h2h, (const char*)xlr, (const char*)xlr + 1024, att3, b3, csr, rowstart,
      perm, out, nullptr);
}